// Round 2
// baseline (4916.226 us; speedup 1.0000x reference)
//
#include <hip/hip_runtime.h>

#define D 256
#define T 4
#define NS 64

typedef unsigned int uint32;

// ---- bf16 helpers (manual RNE, no API dependence) -------------------------
__device__ __forceinline__ float bflo(uint32 u) { return __uint_as_float(u << 16); }
__device__ __forceinline__ float bfhi(uint32 u) { return __uint_as_float(u & 0xffff0000u); }
__device__ __forceinline__ unsigned short f2bf(float x) {
    uint32 u = __float_as_uint(x);
    u = u + 0x7FFFu + ((u >> 16) & 1u);
    return (unsigned short)(u >> 16);
}
__device__ __forceinline__ uint32 pack2(float a, float b) {
    return (uint32)f2bf(a) | ((uint32)f2bf(b) << 16);
}

// ---------------------------------------------------------------------------
__global__ void zero_kernel(uint32* __restrict__ p, long long n)
{
    long long i = (long long)blockIdx.x * blockDim.x + threadIdx.x;
    long long st = (long long)gridDim.x * blockDim.x;
    for (; i < n; i += st) p[i] = 0u;
}

// ---------------------------------------------------------------------------
// transformed[z] = feat @ lin_w[z] + lin_b[z]  (fp32 in, bf16 out)
// 128x128 tile, 256 threads, 8x8/thread, cols = tx*4 + q*64 (bank-friendly)
// ---------------------------------------------------------------------------
__global__ __launch_bounds__(256)
void gemm_f32_bf16(const float* __restrict__ A, const float* __restrict__ Bw,
                   const float* __restrict__ bias, unsigned short* __restrict__ C, int M)
{
    __shared__ float As[16][128 + 4];
    __shared__ float Bs[16][128];
    int t = threadIdx.x;
    int tx = t & 15, ty = t >> 4;
    int m0 = blockIdx.x * 128;
    int n0 = blockIdx.y * 128;
    int z = blockIdx.z;
    const float* Bp = Bw + (size_t)z * D * D;
    const float* bp = bias + (size_t)z * D;
    unsigned short* Cp = C + (size_t)z * (size_t)M * D;

    float acc[8][8];
#pragma unroll
    for (int i = 0; i < 8; i++)
#pragma unroll
        for (int j = 0; j < 8; j++) acc[i][j] = 0.f;

    for (int k0 = 0; k0 < D; k0 += 16) {
        // A tile 128x16 -> transposed
        {
            int row = t >> 1, kc = (t & 1) * 8;
            int gm = m0 + row;
            float4 v0 = make_float4(0.f, 0.f, 0.f, 0.f), v1 = v0;
            if (gm < M) {
                const float* rp = A + (size_t)gm * D + k0 + kc;
                v0 = *(const float4*)rp;
                v1 = *(const float4*)(rp + 4);
            }
            As[kc + 0][row] = v0.x; As[kc + 1][row] = v0.y;
            As[kc + 2][row] = v0.z; As[kc + 3][row] = v0.w;
            As[kc + 4][row] = v1.x; As[kc + 5][row] = v1.y;
            As[kc + 6][row] = v1.z; As[kc + 7][row] = v1.w;
        }
        // B tile 16x128
        {
            int brow = t >> 4, bcol = (t & 15) * 8;
            const float* rp = Bp + (size_t)(k0 + brow) * D + n0 + bcol;
            *(float4*)&Bs[brow][bcol]     = *(const float4*)rp;
            *(float4*)&Bs[brow][bcol + 4] = *(const float4*)(rp + 4);
        }
        __syncthreads();
#pragma unroll
        for (int kk = 0; kk < 16; kk++) {
            float a[8], b[8];
            *(float4*)&a[0] = *(const float4*)&As[kk][ty * 8];
            *(float4*)&a[4] = *(const float4*)&As[kk][ty * 8 + 4];
            *(float4*)&b[0] = *(const float4*)&Bs[kk][tx * 4];
            *(float4*)&b[4] = *(const float4*)&Bs[kk][tx * 4 + 64];
#pragma unroll
            for (int i = 0; i < 8; i++)
#pragma unroll
                for (int j = 0; j < 8; j++)
                    acc[i][j] = fmaf(a[i], b[j], acc[i][j]);
        }
        __syncthreads();
    }

#pragma unroll
    for (int i = 0; i < 8; i++) {
        int gm = m0 + ty * 8 + i;
        if (gm >= M) continue;
#pragma unroll
        for (int q = 0; q < 2; q++) {
            int gn = n0 + tx * 4 + q * 64;
            float r0 = acc[i][q * 4 + 0] + bp[gn + 0];
            float r1 = acc[i][q * 4 + 1] + bp[gn + 1];
            float r2 = acc[i][q * 4 + 2] + bp[gn + 2];
            float r3 = acc[i][q * 4 + 3] + bp[gn + 3];
            uint2 o; o.x = pack2(r0, r1); o.y = pack2(r2, r3);
            *(uint2*)(Cp + (size_t)gm * D + gn) = o;
        }
    }
}

// ---------------------------------------------------------------------------
// In-place: Abuf(bf16, Mx256) = Abuf @ W(fp32 256x256) + bias, bf16 out.
// BM=128, BN=256 (full width), ONE block per row stripe -> in-place safe.
// ---------------------------------------------------------------------------
__global__ __launch_bounds__(256)
void gemm_bf16_inplace(unsigned short* Abuf, const float* __restrict__ Bw,
                       const float* __restrict__ bias, int M)
{
    __shared__ float As[16][128 + 4];
    __shared__ float Bs[16][256];
    int t = threadIdx.x;
    int tx = t & 15, ty = t >> 4;
    int m0 = blockIdx.x * 128;

    float acc[8][16];
#pragma unroll
    for (int i = 0; i < 8; i++)
#pragma unroll
        for (int j = 0; j < 16; j++) acc[i][j] = 0.f;

    for (int k0 = 0; k0 < D; k0 += 16) {
        {
            int row = t >> 1, kc = (t & 1) * 8;
            int gm = m0 + row;
            float a8[8] = {0.f, 0.f, 0.f, 0.f, 0.f, 0.f, 0.f, 0.f};
            if (gm < M) {
                uint4 q = *(const uint4*)(Abuf + (size_t)gm * D + k0 + kc);
                a8[0] = bflo(q.x); a8[1] = bfhi(q.x);
                a8[2] = bflo(q.y); a8[3] = bfhi(q.y);
                a8[4] = bflo(q.z); a8[5] = bfhi(q.z);
                a8[6] = bflo(q.w); a8[7] = bfhi(q.w);
            }
#pragma unroll
            for (int j = 0; j < 8; j++) As[kc + j][row] = a8[j];
        }
        {
            int brow = t >> 4, bcol = (t & 15) * 16;
            const float* rp = Bw + (size_t)(k0 + brow) * D + bcol;
            *(float4*)&Bs[brow][bcol]      = *(const float4*)rp;
            *(float4*)&Bs[brow][bcol + 4]  = *(const float4*)(rp + 4);
            *(float4*)&Bs[brow][bcol + 8]  = *(const float4*)(rp + 8);
            *(float4*)&Bs[brow][bcol + 12] = *(const float4*)(rp + 12);
        }
        __syncthreads();
#pragma unroll
        for (int kk = 0; kk < 16; kk++) {
            float a[8], b[16];
            *(float4*)&a[0] = *(const float4*)&As[kk][ty * 8];
            *(float4*)&a[4] = *(const float4*)&As[kk][ty * 8 + 4];
#pragma unroll
            for (int q = 0; q < 4; q++)
                *(float4*)&b[q * 4] = *(const float4*)&Bs[kk][tx * 4 + q * 64];
#pragma unroll
            for (int i = 0; i < 8; i++)
#pragma unroll
                for (int j = 0; j < 16; j++)
                    acc[i][j] = fmaf(a[i], b[j], acc[i][j]);
        }
        __syncthreads();
    }

#pragma unroll
    for (int i = 0; i < 8; i++) {
        int gm = m0 + ty * 8 + i;
        if (gm >= M) continue;
#pragma unroll
        for (int q = 0; q < 4; q++) {
            int gn = tx * 4 + q * 64;
            float r0 = acc[i][q * 4 + 0] + bias[gn + 0];
            float r1 = acc[i][q * 4 + 1] + bias[gn + 1];
            float r2 = acc[i][q * 4 + 2] + bias[gn + 2];
            float r3 = acc[i][q * 4 + 3] + bias[gn + 3];
            uint2 o; o.x = pack2(r0, r1); o.y = pack2(r2, r3);
            *(uint2*)(Abuf + (size_t)gm * D + gn) = o;
        }
    }
}

// ---------------------------------------------------------------------------
__global__ __launch_bounds__(256)
void tinv_kernel(const unsigned short* __restrict__ tr, float* __restrict__ tinv, int rows)
{
    int wave = threadIdx.x >> 6, lane = threadIdx.x & 63;
    int r = blockIdx.x * 4 + wave;
    if (r >= rows) return;
    uint2 q = *(const uint2*)(tr + (size_t)r * D + lane * 4);
    float a = bflo(q.x), b = bfhi(q.x), c = bflo(q.y), d = bfhi(q.y);
    float s = a * a + b * b + c * c + d * d;
#pragma unroll
    for (int off = 32; off; off >>= 1) s += __shfl_xor(s, off);
    if (lane == 0) tinv[r] = 1.f / fmaxf(sqrtf(s), 1e-8f);
}

// ---------------------------------------------------------------------------
__global__ __launch_bounds__(256)
void sim_kernel(const int* __restrict__ src, const int* __restrict__ dst,
                const float* __restrict__ feat, const unsigned short* __restrict__ tr,
                const float* __restrict__ tinv, int* __restrict__ best, int E, int Nn)
{
    int wave = threadIdx.x >> 6, lane = threadIdx.x & 63;
    int e = blockIdx.x * 4 + wave;
    if (e >= E) return;
    int s = src[e], d = dst[e];
    float4 f4 = *(const float4*)(feat + (size_t)s * D + lane * 4);
    float p[T];
#pragma unroll
    for (int i = 0; i < T; i++) {
        uint2 q = *(const uint2*)(tr + ((size_t)i * Nn + d) * D + lane * 4);
        p[i] = f4.x * bflo(q.x) + f4.y * bfhi(q.x) + f4.z * bflo(q.y) + f4.w * bfhi(q.y);
    }
#pragma unroll
    for (int off = 32; off; off >>= 1) {
#pragma unroll
        for (int i = 0; i < T; i++) p[i] += __shfl_xor(p[i], off);
    }
    if (lane == 0) {
        float bv = -1e30f; int bi = 0;
#pragma unroll
        for (int i = 0; i < T; i++) {
            float v = p[i] * tinv[(size_t)i * Nn + d];
            if (v > bv) { bv = v; bi = i; }   // strict >: first-index ties like jnp.argmax
        }
        best[e] = bi;
    }
}

// ---------------------------------------------------------------------------
// unified edge list: [0,E) copy1, [E,2E) rewired copy, [2E,2E+T*N) identity,
// then n_total self loops. keep == (reference weight != 0).
// ---------------------------------------------------------------------------
__device__ __forceinline__ void decode_edge(int e, const int* __restrict__ src,
                                            const int* __restrict__ dst,
                                            const int* __restrict__ best,
                                            int E, int Nn, int& s, int& d, bool& keep)
{
    if (e < E) { s = src[e]; d = dst[e]; keep = (s != d); }
    else if (e < 2 * E) {
        int k = e - E; s = src[k]; d = dst[k] + best[k] * Nn; keep = (s != d);
    } else if (e < 2 * E + T * Nn) {
        int k = e - 2 * E; int i = k / Nn; int n = k - i * Nn;
        s = n; d = n + i * Nn; keep = (i != 0);
    } else {
        int v = e - (2 * E + T * Nn); s = v; d = v; keep = true;
    }
}

__global__ void hist_kernel(const int* __restrict__ src, const int* __restrict__ dst,
                            const int* __restrict__ best, int* __restrict__ cnt,
                            int E, int Nn)
{
    int total = 2 * E + (2 * T + 1) * Nn;
    for (int e = blockIdx.x * blockDim.x + threadIdx.x; e < total;
         e += gridDim.x * blockDim.x) {
        int s, d; bool keep;
        decode_edge(e, src, dst, best, E, Nn, s, d, keep);
        if (keep) atomicAdd(cnt + d, 1);
    }
}

__global__ void dinv_kernel(const int* __restrict__ cnt, float* __restrict__ dinv, int n)
{
    int v = blockIdx.x * blockDim.x + threadIdx.x;
    if (v < n) dinv[v] = (cnt[v] > 0) ? rsqrtf((float)cnt[v]) : 0.f;
}

__global__ void scan_sums(const int* __restrict__ cnt, int* __restrict__ aux, int n)
{
    __shared__ int sd[256];
    int idx = blockIdx.x * 256 + threadIdx.x;
    sd[threadIdx.x] = (idx < n) ? cnt[idx] : 0;
    __syncthreads();
    for (int off = 128; off; off >>= 1) {
        if (threadIdx.x < off) sd[threadIdx.x] += sd[threadIdx.x + off];
        __syncthreads();
    }
    if (threadIdx.x == 0) aux[blockIdx.x] = sd[0];
}

__global__ void scan_aux(const int* __restrict__ aux, int* __restrict__ auxex, int nb)
{
    __shared__ int sd[1024];
    int t = threadIdx.x;
    int v = (t < nb) ? aux[t] : 0;
    sd[t] = v;
    __syncthreads();
    for (int off = 1; off < 1024; off <<= 1) {
        int x = (t >= off) ? sd[t - off] : 0;
        __syncthreads();
        sd[t] += x;
        __syncthreads();
    }
    if (t < nb) auxex[t] = sd[t] - v;
}

__global__ void scan_write(const int* __restrict__ cnt, const int* __restrict__ auxex,
                           int* __restrict__ rowptr, int n)
{
    __shared__ int sd[256];
    int t = threadIdx.x;
    int idx = blockIdx.x * 256 + t;
    int v = (idx < n) ? cnt[idx] : 0;
    sd[t] = v;
    __syncthreads();
    for (int off = 1; off < 256; off <<= 1) {
        int x = (t >= off) ? sd[t - off] : 0;
        __syncthreads();
        sd[t] += x;
        __syncthreads();
    }
    if (idx < n) {
        int rp = auxex[blockIdx.x] + sd[t] - v;
        rowptr[idx] = rp;
        if (idx == n - 1) rowptr[n] = rp + v;
    }
}

__global__ void scatter_kernel(const int* __restrict__ src, const int* __restrict__ dst,
                               const int* __restrict__ best, const int* __restrict__ rowptr,
                               int* __restrict__ fill, const float* __restrict__ dinv,
                               int* __restrict__ col, float* __restrict__ val,
                               int E, int Nn)
{
    int total = 2 * E + (2 * T + 1) * Nn;
    for (int e = blockIdx.x * blockDim.x + threadIdx.x; e < total;
         e += gridDim.x * blockDim.x) {
        int s, d; bool keep;
        decode_edge(e, src, dst, best, E, Nn, s, d, keep);
        if (keep) {
            int pos = rowptr[d] + atomicAdd(fill + d, 1);
            col[pos] = s;
            val[pos] = dinv[s] * dinv[d];
        }
    }
}

// ---------------------------------------------------------------------------
// aggregate-first: out[v] = sum_j val[j] * relu(x[col[j]])   (bf16 out, no bias)
// MODE 0: x = concat(feat fp32 [0,split), transformed bf16)   MODE 1: x = bf16 buf
// ---------------------------------------------------------------------------
template<int MODE>
__global__ __launch_bounds__(256)
void agg_kernel(const int* __restrict__ rowptr, const int* __restrict__ col,
                const float* __restrict__ val, const float* __restrict__ featf,
                const unsigned short* __restrict__ xb, int split,
                unsigned short* __restrict__ outb, int n_total)
{
    int wave = threadIdx.x >> 6, lane = threadIdx.x & 63;
    int v = blockIdx.x * 4 + wave;
    if (v >= n_total) return;
    int j0 = rowptr[v], j1 = rowptr[v + 1];
    float ax = 0.f, ay = 0.f, az = 0.f, aw = 0.f;
    for (int j = j0; j < j1; j++) {
        int s = col[j];
        float w = val[j];
        float x0, x1, x2, x3;
        if (MODE == 0 && s < split) {
            float4 f = *(const float4*)(featf + (size_t)s * D + lane * 4);
            x0 = f.x; x1 = f.y; x2 = f.z; x3 = f.w;
        } else {
            const unsigned short* p = (MODE == 0) ? (xb + (size_t)(s - split) * D)
                                                  : (xb + (size_t)s * D);
            uint2 q = *(const uint2*)(p + lane * 4);
            x0 = bflo(q.x); x1 = bfhi(q.x); x2 = bflo(q.y); x3 = bfhi(q.y);
        }
        ax = fmaf(w, fmaxf(x0, 0.f), ax);
        ay = fmaf(w, fmaxf(x1, 0.f), ay);
        az = fmaf(w, fmaxf(x2, 0.f), az);
        aw = fmaf(w, fmaxf(x3, 0.f), aw);
    }
    uint2 o; o.x = pack2(ax, ay); o.y = pack2(az, aw);
    *(uint2*)(outb + (size_t)v * D + lane * 4) = o;
}

// ---------------------------------------------------------------------------
// classes = argmax(relu(af2) @ lin1 + b); H[n, cls] += 1  (logits never stored)
// ---------------------------------------------------------------------------
__global__ __launch_bounds__(256)
void logits_argmax(const unsigned short* __restrict__ af2, const float* __restrict__ Wl,
                   const float* __restrict__ bl, float* __restrict__ H, int Mrows, int Nn)
{
    __shared__ float Ws[D * NS];   // 64 KiB exactly
    int t = threadIdx.x;
#pragma unroll
    for (int i = 0; i < 16; i++)
        ((float4*)Ws)[t + i * 256] = ((const float4*)Wl)[t + i * 256];
    __syncthreads();
    int wave = t >> 6, lane = t & 63;
    float bc = bl[lane];
    int rbase = blockIdx.x * 16 + wave;
    for (int rr = 0; rr < 4; rr++) {
        int r = rbase + rr * 4;
        if (r >= Mrows) break;
        uint2 q = *(const uint2*)(af2 + (size_t)r * D + lane * 4);
        float x0 = fmaxf(bflo(q.x), 0.f), x1 = fmaxf(bfhi(q.x), 0.f);
        float x2 = fmaxf(bflo(q.y), 0.f), x3 = fmaxf(bfhi(q.y), 0.f);
        float acc = bc;
#pragma unroll
        for (int kk = 0; kk < 64; kk++) {
            float xa = __shfl(x0, kk), xb = __shfl(x1, kk);
            float xc = __shfl(x2, kk), xd = __shfl(x3, kk);
            const float* lp = Ws + (kk * 4) * NS + lane;
            acc = fmaf(xa, lp[0], acc);
            acc = fmaf(xb, lp[NS], acc);
            acc = fmaf(xc, lp[2 * NS], acc);
            acc = fmaf(xd, lp[3 * NS], acc);
        }
        float bv = acc; int bi = lane;
#pragma unroll
        for (int off = 32; off; off >>= 1) {
            float ov = __shfl_xor(bv, off);
            int   oi = __shfl_xor(bi, off);
            if (ov > bv || (ov == bv && oi < bi)) { bv = ov; bi = oi; }
        }
        if (lane == 0) atomicAdd(H + (size_t)(r % Nn) * NS + bi, 1.0f);
    }
}

// ---------------------------------------------------------------------------
// he[c] = sum_{n: H[n,c]>0} af2[n]   (one wave per block, 128 nodes/block)
// ---------------------------------------------------------------------------
__global__ __launch_bounds__(64)
void he_kernel(const float* __restrict__ H, const unsigned short* __restrict__ af2,
               float* __restrict__ he, int Nn)
{
    __shared__ float acc[NS * D];   // 64 KiB exactly
    int lane = threadIdx.x;
    for (int i = lane * 4; i < NS * D; i += 256)
        *(float4*)(acc + i) = make_float4(0.f, 0.f, 0.f, 0.f);
    __syncthreads();
    int n0 = blockIdx.x * 128;
    int n1 = min(n0 + 128, Nn);
    for (int n = n0; n < n1; n++) {
        float hv = H[(size_t)n * NS + lane];
        unsigned long long m = __ballot(hv > 0.f);
        if (!m) continue;
        uint2 q = *(const uint2*)(af2 + (size_t)n * D + lane * 4);
        float x0 = bflo(q.x), x1 = bfhi(q.x), x2 = bflo(q.y), x3 = bfhi(q.y);
        while (m) {
            int c = __ffsll(m) - 1;
            m &= m - 1;
            float* p = acc + (size_t)c * D + lane * 4;
            p[0] += x0; p[1] += x1; p[2] += x2; p[3] += x3;
        }
    }
    __syncthreads();
    for (int i = lane; i < NS * D; i += 64) atomicAdd(he + i, acc[i]);
}

// ---------------------------------------------------------------------------
// BigB[rho=0][d][c] = he[c][d];  BigB[t+1][d][c] = sum_k lin_w[t,d,k]*he[c,k]
// beta[t+1][c] = sum_k lin_b[t,k]*he[c,k]   (beta[0]=0, pre-zeroed)
// ---------------------------------------------------------------------------
__global__ void bigb_copy(const float* __restrict__ he, float* __restrict__ BigB)
{
    int idx = blockIdx.x * 256 + threadIdx.x;
    if (idx < D * NS) {
        int d = idx >> 6, c = idx & 63;
        BigB[idx] = he[(size_t)c * D + d];
    }
}

__global__ __launch_bounds__(256)
void bigb_mm(const float* __restrict__ lin_w, const float* __restrict__ lin_b,
             const float* __restrict__ he, float* __restrict__ BigB,
             float* __restrict__ beta)
{
    int gw = (int)((blockIdx.x * 256 + threadIdx.x) >> 6);
    int lane = threadIdx.x & 63;
    const int totalA = T * D * NS;
    if (gw >= totalA + T * NS) return;
    const float* xrow; const float* hrow; float* outp;
    if (gw < totalA) {
        int t = gw / (D * NS); int rem = gw - t * D * NS;
        int d = rem / NS; int c = rem - d * NS;
        xrow = lin_w + ((size_t)t * D + d) * D;
        hrow = he + (size_t)c * D;
        outp = BigB + ((size_t)(t + 1) * D + d) * NS + c;
    } else {
        int i = gw - totalA; int t = i / NS; int c = i - t * NS;
        xrow = lin_b + (size_t)t * D;
        hrow = he + (size_t)c * D;
        outp = beta + (size_t)(t + 1) * NS + c;
    }
    float4 x = *(const float4*)(xrow + lane * 4);
    float4 h = *(const float4*)(hrow + lane * 4);
    float s = x.x * h.x + x.y * h.y + x.z * h.z + x.w * h.w;
#pragma unroll
    for (int off = 32; off; off >>= 1) s += __shfl_xor(s, off);
    if (lane == 0) *outp = s;
}

// ---------------------------------------------------------------------------
// dots[rho*Nn+n, c] = (feat[n] . BigB[rho][:,c] + beta[rho][c]) * 1/16
// ---------------------------------------------------------------------------
__global__ __launch_bounds__(256)
void dots2_kernel(const float* __restrict__ feat, const float* __restrict__ BigB,
                  const float* __restrict__ beta, float* __restrict__ dots, int Nn)
{
    __shared__ float Ls[D * NS];   // 64 KiB exactly
    int t = threadIdx.x, wave = t >> 6, lane = t & 63;
    int nbase = blockIdx.x * 64 + wave * 16;
    for (int rho = 0; rho < T + 1; rho++) {
        __syncthreads();
        const float4* srcp = (const float4*)(BigB + (size_t)rho * D * NS);
#pragma unroll
        for (int i = 0; i < 16; i++) ((float4*)Ls)[t + i * 256] = srcp[t + i * 256];
        __syncthreads();
        float bb = beta[rho * NS + lane];
        for (int rr = 0; rr < 16; rr++) {
            int n = nbase + rr;
            if (n >= Nn) break;
            float4 x = *(const float4*)(feat + (size_t)n * D + lane * 4);
            float acc = bb;
#pragma unroll
            for (int kk = 0; kk < 64; kk++) {
                float xa = __shfl(x.x, kk), xb = __shfl(x.y, kk);
                float xc = __shfl(x.z, kk), xd = __shfl(x.w, kk);
                const float* lp = Ls + (kk * 4) * NS + lane;
                acc = fmaf(xa, lp[0], acc);
                acc = fmaf(xb, lp[NS], acc);
                acc = fmaf(xc, lp[2 * NS], acc);
                acc = fmaf(xd, lp[3 * NS], acc);
            }
            dots[((size_t)rho * Nn + n) * NS + lane] = acc * 0.0625f;
        }
    }
}

// ---------------------------------------------------------------------------
extern "C" void kernel_launch(void* const* d_in, const int* in_sizes, int n_in,
                              void* d_out, int out_size, void* d_ws, size_t ws_size,
                              hipStream_t stream)
{
    const int*   edge_index = (const int*)d_in[0];
    const float* features   = (const float*)d_in[1];
    const float* lin_w      = (const float*)d_in[2];
    const float* lin_b      = (const float*)d_in[3];
    const float* gcn0_w     = (const float*)d_in[4];
    const float* gcn0_b     = (const float*)d_in[5];
    const float* gcn1_w     = (const float*)d_in[6];
    const float* gcn1_b     = (const float*)d_in[7];
    const float* lin1_w     = (const float*)d_in[8];
    const float* lin1_b     = (const float*)d_in[9];

    int E  = in_sizes[0] / 2;
    int Nn = in_sizes[1] / D;
    int n_total = (T + 1) * Nn;
    int Mrep = T * Nn;
    int colcap = 2 * E + (2 * T + 1) * Nn;

    const int* src = edge_index;
    const int* dst = edge_index + E;

    float* out_H    = (float*)d_out;
    float* out_he   = out_H + (size_t)Nn * NS;
    float* out_dots = out_he + (size_t)NS * D;

    // ---- workspace carve: only the two big bf16 regions + BigB (~256.3 MB)
    char* ws = (char*)d_ws;
    auto carve = [&](size_t bytes) {
        char* p = ws; ws += (bytes + 255) & ~(size_t)255; return p;
    };
    unsigned short* R1   = (unsigned short*)carve((size_t)n_total * D * 2); // agg0 -> h
    unsigned short* R2   = (unsigned short*)carve((size_t)n_total * D * 2); // transformed -> agg1 -> af2
    float*          BigB = (float*)carve((size_t)(T + 1) * D * NS * 4);
    float*          beta = (float*)carve((size_t)(T + 1) * NS * 4);
    unsigned short* transformed = R2;   // prefix: Mrep*D bf16, dead before agg1

    // ---- small scratch lives in the out_dots region (dead until dots2,
    //      which fully overwrites it at the very end)
    char* sc = (char*)out_dots;
    auto carve2 = [&](size_t bytes) {
        char* p = sc; sc += (bytes + 255) & ~(size_t)255; return p;
    };
    float* tinv   = (float*)carve2((size_t)Mrep * 4);
    int*   best   = (int*)carve2((size_t)E * 4);
    int*   cnt    = (int*)carve2((size_t)n_total * 4);
    int*   rowptr = (int*)carve2((size_t)(n_total + 1) * 4);
    int*   fill   = (int*)carve2((size_t)n_total * 4);
    float* dinv   = (float*)carve2((size_t)n_total * 4);
    int*   aux    = (int*)carve2(1024 * 4);
    int*   auxex  = (int*)carve2(1024 * 4);
    int*   col    = (int*)carve2((size_t)colcap * 4);
    float* val    = (float*)carve2((size_t)colcap * 4);

    // ---- zero the accumulators (ws/out are poisoned before every launch)
    zero_kernel<<<512, 256, 0, stream>>>((uint32*)cnt, n_total);
    zero_kernel<<<512, 256, 0, stream>>>((uint32*)fill, n_total);
    zero_kernel<<<512, 256, 0, stream>>>((uint32*)out_H, (long long)Nn * NS + NS * D);
    zero_kernel<<<1, 256, 0, stream>>>((uint32*)beta, (T + 1) * NS);

    // 1. transformed[t] = feat @ lin_w[t] + lin_b[t]   (bf16 out)
    dim3 g0((Nn + 127) / 128, 2, T);
    gemm_f32_bf16<<<g0, 256, 0, stream>>>(features, lin_w, lin_b, transformed, Nn);

    // 2/3. row norms + per-edge best replica
    tinv_kernel<<<(Mrep + 3) / 4, 256, 0, stream>>>(transformed, tinv, Mrep);
    sim_kernel<<<(E + 3) / 4, 256, 0, stream>>>(src, dst, features, transformed,
                                                tinv, best, E, Nn);

    // 4. CSR build (deg == cnt)
    hist_kernel<<<2048, 256, 0, stream>>>(src, dst, best, cnt, E, Nn);
    dinv_kernel<<<(n_total + 255) / 256, 256, 0, stream>>>(cnt, dinv, n_total);
    int nb = (n_total + 255) / 256;
    scan_sums<<<nb, 256, 0, stream>>>(cnt, aux, n_total);
    scan_aux<<<1, 1024, 0, stream>>>(aux, auxex, nb);
    scan_write<<<nb, 256, 0, stream>>>(cnt, auxex, rowptr, n_total);
    scatter_kernel<<<2048, 256, 0, stream>>>(src, dst, best, rowptr, fill, dinv,
                                             col, val, E, Nn);

    // 5. layer 0: agg0 = Agg(relu(concat(feat, transformed))) -> R1; h = agg0@W0+b0 in-place
    agg_kernel<0><<<(n_total + 3) / 4, 256, 0, stream>>>(rowptr, col, val, features,
                                                         transformed, Nn, R1, n_total);
    gemm_bf16_inplace<<<(n_total + 127) / 128, 256, 0, stream>>>(R1, gcn0_w, gcn0_b, n_total);

    // 6. layer 1: agg1 = Agg(relu(h)) -> R2 (transformed is dead); af2 = agg1@W1+b1 in-place
    agg_kernel<1><<<(n_total + 3) / 4, 256, 0, stream>>>(rowptr, col, val, nullptr,
                                                         R1, 0, R2, n_total);
    gemm_bf16_inplace<<<(n_total + 127) / 128, 256, 0, stream>>>(R2, gcn1_w, gcn1_b, n_total);

    // 7. classes + H
    logits_argmax<<<(n_total + 15) / 16, 256, 0, stream>>>(R2, lin1_w, lin1_b,
                                                           out_H, n_total, Nn);
    // 8. hyperedge features (af2 base rows = R2 prefix)
    he_kernel<<<(Nn + 127) / 128, 64, 0, stream>>>(out_H, R2, out_he, Nn);

    // 9. dots = feat @ [he^T | lin_w[t]@he^T] + beta, scaled
    bigb_copy<<<(D * NS + 255) / 256, 256, 0, stream>>>(out_he, BigB);
    bigb_mm<<<(T * D * NS + T * NS + 3) / 4, 256, 0, stream>>>(lin_w, lin_b, out_he,
                                                               BigB, beta);
    dots2_kernel<<<(Nn + 63) / 64, 256, 0, stream>>>(features, BigB, beta,
                                                     out_dots, Nn);
}

// Round 3
// 3062.538 us; speedup vs baseline: 1.6053x; 1.6053x over previous
//
#include <hip/hip_runtime.h>

#define D 256
#define T 4
#define NS 64

typedef unsigned int uint32;

// ---- bf16 helpers (manual RNE, no API dependence) -------------------------
__device__ __forceinline__ float bflo(uint32 u) { return __uint_as_float(u << 16); }
__device__ __forceinline__ float bfhi(uint32 u) { return __uint_as_float(u & 0xffff0000u); }
__device__ __forceinline__ unsigned short f2bf(float x) {
    uint32 u = __float_as_uint(x);
    u = u + 0x7FFFu + ((u >> 16) & 1u);
    return (unsigned short)(u >> 16);
}
__device__ __forceinline__ uint32 pack2(float a, float b) {
    return (uint32)f2bf(a) | ((uint32)f2bf(b) << 16);
}

// ---------------------------------------------------------------------------
__global__ void zero_kernel(uint32* __restrict__ p, long long n)
{
    long long i = (long long)blockIdx.x * blockDim.x + threadIdx.x;
    long long st = (long long)gridDim.x * blockDim.x;
    for (; i < n; i += st) p[i] = 0u;
}

// ---------------------------------------------------------------------------
// transformed[z] = feat @ lin_w[z] + lin_b[z]  (fp32 in, bf16 out)
// ---------------------------------------------------------------------------
__global__ __launch_bounds__(256)
void gemm_f32_bf16(const float* __restrict__ A, const float* __restrict__ Bw,
                   const float* __restrict__ bias, unsigned short* __restrict__ C, int M)
{
    __shared__ float As[16][128 + 4];
    __shared__ float Bs[16][128];
    int t = threadIdx.x;
    int tx = t & 15, ty = t >> 4;
    int m0 = blockIdx.x * 128;
    int n0 = blockIdx.y * 128;
    int z = blockIdx.z;
    const float* Bp = Bw + (size_t)z * D * D;
    const float* bp = bias + (size_t)z * D;
    unsigned short* Cp = C + (size_t)z * (size_t)M * D;

    float acc[8][8];
#pragma unroll
    for (int i = 0; i < 8; i++)
#pragma unroll
        for (int j = 0; j < 8; j++) acc[i][j] = 0.f;

    for (int k0 = 0; k0 < D; k0 += 16) {
        {
            int row = t >> 1, kc = (t & 1) * 8;
            int gm = m0 + row;
            float4 v0 = make_float4(0.f, 0.f, 0.f, 0.f), v1 = v0;
            if (gm < M) {
                const float* rp = A + (size_t)gm * D + k0 + kc;
                v0 = *(const float4*)rp;
                v1 = *(const float4*)(rp + 4);
            }
            As[kc + 0][row] = v0.x; As[kc + 1][row] = v0.y;
            As[kc + 2][row] = v0.z; As[kc + 3][row] = v0.w;
            As[kc + 4][row] = v1.x; As[kc + 5][row] = v1.y;
            As[kc + 6][row] = v1.z; As[kc + 7][row] = v1.w;
        }
        {
            int brow = t >> 4, bcol = (t & 15) * 8;
            const float* rp = Bp + (size_t)(k0 + brow) * D + n0 + bcol;
            *(float4*)&Bs[brow][bcol]     = *(const float4*)rp;
            *(float4*)&Bs[brow][bcol + 4] = *(const float4*)(rp + 4);
        }
        __syncthreads();
#pragma unroll
        for (int kk = 0; kk < 16; kk++) {
            float a[8], b[8];
            *(float4*)&a[0] = *(const float4*)&As[kk][ty * 8];
            *(float4*)&a[4] = *(const float4*)&As[kk][ty * 8 + 4];
            *(float4*)&b[0] = *(const float4*)&Bs[kk][tx * 4];
            *(float4*)&b[4] = *(const float4*)&Bs[kk][tx * 4 + 64];
#pragma unroll
            for (int i = 0; i < 8; i++)
#pragma unroll
                for (int j = 0; j < 8; j++)
                    acc[i][j] = fmaf(a[i], b[j], acc[i][j]);
        }
        __syncthreads();
    }

#pragma unroll
    for (int i = 0; i < 8; i++) {
        int gm = m0 + ty * 8 + i;
        if (gm >= M) continue;
#pragma unroll
        for (int q = 0; q < 2; q++) {
            int gn = n0 + tx * 4 + q * 64;
            float r0 = acc[i][q * 4 + 0] + bp[gn + 0];
            float r1 = acc[i][q * 4 + 1] + bp[gn + 1];
            float r2 = acc[i][q * 4 + 2] + bp[gn + 2];
            float r3 = acc[i][q * 4 + 3] + bp[gn + 3];
            uint2 o; o.x = pack2(r0, r1); o.y = pack2(r2, r3);
            *(uint2*)(Cp + (size_t)gm * D + gn) = o;
        }
    }
}

// ---------------------------------------------------------------------------
// In-place: Abuf(bf16, Mx256) = Abuf @ W(fp32 256x256) + bias, bf16 out.
// BM=128, BN=256 (full width), ONE block per row stripe -> in-place safe.
// ---------------------------------------------------------------------------
__global__ __launch_bounds__(256)
void gemm_bf16_inplace(unsigned short* Abuf, const float* __restrict__ Bw,
                       const float* __restrict__ bias, int M)
{
    __shared__ float As[16][128 + 4];
    __shared__ float Bs[16][256];
    int t = threadIdx.x;
    int tx = t & 15, ty = t >> 4;
    int m0 = blockIdx.x * 128;

    float acc[8][16];
#pragma unroll
    for (int i = 0; i < 8; i++)
#pragma unroll
        for (int j = 0; j < 16; j++) acc[i][j] = 0.f;

    for (int k0 = 0; k0 < D; k0 += 16) {
        {
            int row = t >> 1, kc = (t & 1) * 8;
            int gm = m0 + row;
            float a8[8] = {0.f, 0.f, 0.f, 0.f, 0.f, 0.f, 0.f, 0.f};
            if (gm < M) {
                uint4 q = *(const uint4*)(Abuf + (size_t)gm * D + k0 + kc);
                a8[0] = bflo(q.x); a8[1] = bfhi(q.x);
                a8[2] = bflo(q.y); a8[3] = bfhi(q.y);
                a8[4] = bflo(q.z); a8[5] = bfhi(q.z);
                a8[6] = bflo(q.w); a8[7] = bfhi(q.w);
            }
#pragma unroll
            for (int j = 0; j < 8; j++) As[kc + j][row] = a8[j];
        }
        {
            int brow = t >> 4, bcol = (t & 15) * 16;
            const float* rp = Bw + (size_t)(k0 + brow) * D + bcol;
            *(float4*)&Bs[brow][bcol]      = *(const float4*)rp;
            *(float4*)&Bs[brow][bcol + 4]  = *(const float4*)(rp + 4);
            *(float4*)&Bs[brow][bcol + 8]  = *(const float4*)(rp + 8);
            *(float4*)&Bs[brow][bcol + 12] = *(const float4*)(rp + 12);
        }
        __syncthreads();
#pragma unroll
        for (int kk = 0; kk < 16; kk++) {
            float a[8], b[16];
            *(float4*)&a[0] = *(const float4*)&As[kk][ty * 8];
            *(float4*)&a[4] = *(const float4*)&As[kk][ty * 8 + 4];
#pragma unroll
            for (int q = 0; q < 4; q++)
                *(float4*)&b[q * 4] = *(const float4*)&Bs[kk][tx * 4 + q * 64];
#pragma unroll
            for (int i = 0; i < 8; i++)
#pragma unroll
                for (int j = 0; j < 16; j++)
                    acc[i][j] = fmaf(a[i], b[j], acc[i][j]);
        }
        __syncthreads();
    }

#pragma unroll
    for (int i = 0; i < 8; i++) {
        int gm = m0 + ty * 8 + i;
        if (gm >= M) continue;
#pragma unroll
        for (int q = 0; q < 4; q++) {
            int gn = tx * 4 + q * 64;
            float r0 = acc[i][q * 4 + 0] + bias[gn + 0];
            float r1 = acc[i][q * 4 + 1] + bias[gn + 1];
            float r2 = acc[i][q * 4 + 2] + bias[gn + 2];
            float r3 = acc[i][q * 4 + 3] + bias[gn + 3];
            uint2 o; o.x = pack2(r0, r1); o.y = pack2(r2, r3);
            *(uint2*)(Abuf + (size_t)gm * D + gn) = o;
        }
    }
}

// ---------------------------------------------------------------------------
__global__ __launch_bounds__(256)
void tinv_kernel(const unsigned short* __restrict__ tr, float* __restrict__ tinv, int rows)
{
    int wave = threadIdx.x >> 6, lane = threadIdx.x & 63;
    int r = blockIdx.x * 4 + wave;
    if (r >= rows) return;
    uint2 q = *(const uint2*)(tr + (size_t)r * D + lane * 4);
    float a = bflo(q.x), b = bfhi(q.x), c = bflo(q.y), d = bfhi(q.y);
    float s = a * a + b * b + c * c + d * d;
#pragma unroll
    for (int off = 32; off; off >>= 1) s += __shfl_xor(s, off);
    if (lane == 0) tinv[r] = 1.f / fmaxf(sqrtf(s), 1e-8f);
}

// ---------------------------------------------------------------------------
__global__ __launch_bounds__(256)
void sim_kernel(const int* __restrict__ src, const int* __restrict__ dst,
                const float* __restrict__ feat, const unsigned short* __restrict__ tr,
                const float* __restrict__ tinv, int* __restrict__ best, int E, int Nn)
{
    int wave = threadIdx.x >> 6, lane = threadIdx.x & 63;
    int e = blockIdx.x * 4 + wave;
    if (e >= E) return;
    int s = src[e], d = dst[e];
    float4 f4 = *(const float4*)(feat + (size_t)s * D + lane * 4);
    float p[T];
#pragma unroll
    for (int i = 0; i < T; i++) {
        uint2 q = *(const uint2*)(tr + ((size_t)i * Nn + d) * D + lane * 4);
        p[i] = f4.x * bflo(q.x) + f4.y * bfhi(q.x) + f4.z * bflo(q.y) + f4.w * bfhi(q.y);
    }
#pragma unroll
    for (int off = 32; off; off >>= 1) {
#pragma unroll
        for (int i = 0; i < T; i++) p[i] += __shfl_xor(p[i], off);
    }
    if (lane == 0) {
        float bv = -1e30f; int bi = 0;
#pragma unroll
        for (int i = 0; i < T; i++) {
            float v = p[i] * tinv[(size_t)i * Nn + d];
            if (v > bv) { bv = v; bi = i; }   // strict >: first-index ties like jnp.argmax
        }
        best[e] = bi;
    }
}

// ---------------------------------------------------------------------------
// unified edge list: [0,E) copy1, [E,2E) rewired copy, [2E,2E+T*N) identity,
// then n_total self loops. keep == (reference weight != 0).
// ---------------------------------------------------------------------------
__device__ __forceinline__ void decode_edge(int e, const int* __restrict__ src,
                                            const int* __restrict__ dst,
                                            const int* __restrict__ best,
                                            int E, int Nn, int& s, int& d, bool& keep)
{
    if (e < E) { s = src[e]; d = dst[e]; keep = (s != d); }
    else if (e < 2 * E) {
        int k = e - E; s = src[k]; d = dst[k] + best[k] * Nn; keep = (s != d);
    } else if (e < 2 * E + T * Nn) {
        int k = e - 2 * E; int i = k / Nn; int n = k - i * Nn;
        s = n; d = n + i * Nn; keep = (i != 0);
    } else {
        int v = e - (2 * E + T * Nn); s = v; d = v; keep = true;
    }
}

__global__ void hist_kernel(const int* __restrict__ src, const int* __restrict__ dst,
                            const int* __restrict__ best, int* __restrict__ cnt,
                            int E, int Nn)
{
    int total = 2 * E + (2 * T + 1) * Nn;
    for (int e = blockIdx.x * blockDim.x + threadIdx.x; e < total;
         e += gridDim.x * blockDim.x) {
        int s, d; bool keep;
        decode_edge(e, src, dst, best, E, Nn, s, d, keep);
        if (keep) atomicAdd(cnt + d, 1);
    }
}

__global__ void dinv_kernel(const int* __restrict__ cnt, float* __restrict__ dinv, int n)
{
    int v = blockIdx.x * blockDim.x + threadIdx.x;
    if (v < n) dinv[v] = (cnt[v] > 0) ? rsqrtf((float)cnt[v]) : 0.f;
}

__global__ void scan_sums(const int* __restrict__ cnt, int* __restrict__ aux, int n)
{
    __shared__ int sd[256];
    int idx = blockIdx.x * 256 + threadIdx.x;
    sd[threadIdx.x] = (idx < n) ? cnt[idx] : 0;
    __syncthreads();
    for (int off = 128; off; off >>= 1) {
        if (threadIdx.x < off) sd[threadIdx.x] += sd[threadIdx.x + off];
        __syncthreads();
    }
    if (threadIdx.x == 0) aux[blockIdx.x] = sd[0];
}

__global__ void scan_aux(const int* __restrict__ aux, int* __restrict__ auxex, int nb)
{
    __shared__ int sd[1024];
    int t = threadIdx.x;
    int v = (t < nb) ? aux[t] : 0;
    sd[t] = v;
    __syncthreads();
    for (int off = 1; off < 1024; off <<= 1) {
        int x = (t >= off) ? sd[t - off] : 0;
        __syncthreads();
        sd[t] += x;
        __syncthreads();
    }
    if (t < nb) auxex[t] = sd[t] - v;
}

__global__ void scan_write(const int* __restrict__ cnt, const int* __restrict__ auxex,
                           int* __restrict__ rowptr, int n)
{
    __shared__ int sd[256];
    int t = threadIdx.x;
    int idx = blockIdx.x * 256 + t;
    int v = (idx < n) ? cnt[idx] : 0;
    sd[t] = v;
    __syncthreads();
    for (int off = 1; off < 256; off <<= 1) {
        int x = (t >= off) ? sd[t - off] : 0;
        __syncthreads();
        sd[t] += x;
        __syncthreads();
    }
    if (idx < n) {
        int rp = auxex[blockIdx.x] + sd[t] - v;
        rowptr[idx] = rp;
        if (idx == n - 1) rowptr[n] = rp + v;
    }
}

__global__ void scatter_kernel(const int* __restrict__ src, const int* __restrict__ dst,
                               const int* __restrict__ best, const int* __restrict__ rowptr,
                               int* __restrict__ fill, const float* __restrict__ dinv,
                               int* __restrict__ col, float* __restrict__ val,
                               int E, int Nn)
{
    int total = 2 * E + (2 * T + 1) * Nn;
    for (int e = blockIdx.x * blockDim.x + threadIdx.x; e < total;
         e += gridDim.x * blockDim.x) {
        int s, d; bool keep;
        decode_edge(e, src, dst, best, E, Nn, s, d, keep);
        if (keep) {
            int pos = rowptr[d] + atomicAdd(fill + d, 1);
            col[pos] = s;
            val[pos] = dinv[s] * dinv[d];
        }
    }
}

// ---------------------------------------------------------------------------
// aggregate-first: out[v] = sum_j val[j] * relu(x[col[j]])   (bf16 out, no bias)
// MODE 0: x = concat(feat fp32 [0,split), transformed bf16)   MODE 1: x = bf16 buf
// ---------------------------------------------------------------------------
template<int MODE>
__global__ __launch_bounds__(256)
void agg_kernel(const int* __restrict__ rowptr, const int* __restrict__ col,
                const float* __restrict__ val, const float* __restrict__ featf,
                const unsigned short* __restrict__ xb, int split,
                unsigned short* __restrict__ outb, int n_total)
{
    int wave = threadIdx.x >> 6, lane = threadIdx.x & 63;
    int v = blockIdx.x * 4 + wave;
    if (v >= n_total) return;
    int j0 = rowptr[v], j1 = rowptr[v + 1];
    float ax = 0.f, ay = 0.f, az = 0.f, aw = 0.f;
    for (int j = j0; j < j1; j++) {
        int s = col[j];
        float w = val[j];
        float x0, x1, x2, x3;
        if (MODE == 0 && s < split) {
            float4 f = *(const float4*)(featf + (size_t)s * D + lane * 4);
            x0 = f.x; x1 = f.y; x2 = f.z; x3 = f.w;
        } else {
            const unsigned short* p = (MODE == 0) ? (xb + (size_t)(s - split) * D)
                                                  : (xb + (size_t)s * D);
            uint2 q = *(const uint2*)(p + lane * 4);
            x0 = bflo(q.x); x1 = bfhi(q.x); x2 = bflo(q.y); x3 = bfhi(q.y);
        }
        ax = fmaf(w, fmaxf(x0, 0.f), ax);
        ay = fmaf(w, fmaxf(x1, 0.f), ay);
        az = fmaf(w, fmaxf(x2, 0.f), az);
        aw = fmaf(w, fmaxf(x3, 0.f), aw);
    }
    uint2 o; o.x = pack2(ax, ay); o.y = pack2(az, aw);
    *(uint2*)(outb + (size_t)v * D + lane * 4) = o;
}

// ---------------------------------------------------------------------------
// GEMM-style logits + argmax: tile 64 rows x 64 cols, acc 4x4/thread.
// logits = relu(af2)@lin1 + b; argmax over cols (first-index ties); H atomic.
// ---------------------------------------------------------------------------
__global__ __launch_bounds__(256)
void logits_gemm(const unsigned short* __restrict__ af2, const float* __restrict__ Wl,
                 const float* __restrict__ bl, float* __restrict__ H, int Mrows, int Nn)
{
    __shared__ float As[16][64 + 4];
    __shared__ float Bs[16][64];
    __shared__ float Ls[64][68];
    int t = threadIdx.x;
    int tx = t & 15, ty = t >> 4;
    int m0 = blockIdx.x * 64;

    float acc[4][4];
#pragma unroll
    for (int i = 0; i < 4; i++)
#pragma unroll
        for (int j = 0; j < 4; j++) acc[i][j] = 0.f;

    for (int k0 = 0; k0 < D; k0 += 16) {
        {
            int row = t >> 2, c4 = (t & 3) * 4;
            int gm = m0 + row;
            float x0 = 0.f, x1 = 0.f, x2 = 0.f, x3 = 0.f;
            if (gm < Mrows) {
                uint2 q = *(const uint2*)(af2 + (size_t)gm * D + k0 + c4);
                x0 = fmaxf(bflo(q.x), 0.f); x1 = fmaxf(bfhi(q.x), 0.f);
                x2 = fmaxf(bflo(q.y), 0.f); x3 = fmaxf(bfhi(q.y), 0.f);
            }
            As[c4 + 0][row] = x0; As[c4 + 1][row] = x1;
            As[c4 + 2][row] = x2; As[c4 + 3][row] = x3;
        }
        {
            int d = t >> 4, c4 = (t & 15) * 4;
            *(float4*)&Bs[d][c4] = *(const float4*)(Wl + (size_t)(k0 + d) * NS + c4);
        }
        __syncthreads();
#pragma unroll
        for (int kk = 0; kk < 16; kk++) {
            float a[4], b[4];
            *(float4*)&a[0] = *(const float4*)&As[kk][ty * 4];
            *(float4*)&b[0] = *(const float4*)&Bs[kk][tx * 4];
#pragma unroll
            for (int i = 0; i < 4; i++)
#pragma unroll
                for (int j = 0; j < 4; j++)
                    acc[i][j] = fmaf(a[i], b[j], acc[i][j]);
        }
        __syncthreads();
    }

    // + bias, park logits in LDS (row stride 68: float4-aligned, conflict-free)
    float4 bb = *(const float4*)(bl + tx * 4);
#pragma unroll
    for (int i = 0; i < 4; i++) {
        float4 v;
        v.x = acc[i][0] + bb.x; v.y = acc[i][1] + bb.y;
        v.z = acc[i][2] + bb.z; v.w = acc[i][3] + bb.w;
        *(float4*)&Ls[ty * 4 + i][tx * 4] = v;
    }
    __syncthreads();
    if (t < 64) {
        int grow = m0 + t;
        if (grow < Mrows) {
            float bv = -3.4e38f; int bi = 0;
#pragma unroll
            for (int k4 = 0; k4 < 16; k4++) {
                float4 v = *(const float4*)&Ls[t][k4 * 4];
                if (v.x > bv) { bv = v.x; bi = k4 * 4 + 0; }
                if (v.y > bv) { bv = v.y; bi = k4 * 4 + 1; }
                if (v.z > bv) { bv = v.z; bi = k4 * 4 + 2; }
                if (v.w > bv) { bv = v.w; bi = k4 * 4 + 3; }
            }
            atomicAdd(H + (size_t)(grow % Nn) * NS + bi, 1.0f);
        }
    }
}

// ---------------------------------------------------------------------------
// he[c] = sum_{n: H[n,c]>0} af2[n]   (one wave per block, 128 nodes/block)
// ---------------------------------------------------------------------------
__global__ __launch_bounds__(64)
void he_kernel(const float* __restrict__ H, const unsigned short* __restrict__ af2,
               float* __restrict__ he, int Nn)
{
    __shared__ float acc[NS * D];   // 64 KiB exactly
    int lane = threadIdx.x;
    for (int i = lane * 4; i < NS * D; i += 256)
        *(float4*)(acc + i) = make_float4(0.f, 0.f, 0.f, 0.f);
    __syncthreads();
    int n0 = blockIdx.x * 128;
    int n1 = min(n0 + 128, Nn);
    for (int n = n0; n < n1; n++) {
        float hv = H[(size_t)n * NS + lane];
        unsigned long long m = __ballot(hv > 0.f);
        if (!m) continue;
        uint2 q = *(const uint2*)(af2 + (size_t)n * D + lane * 4);
        float x0 = bflo(q.x), x1 = bfhi(q.x), x2 = bflo(q.y), x3 = bfhi(q.y);
        while (m) {
            int c = __ffsll(m) - 1;
            m &= m - 1;
            float* p = acc + (size_t)c * D + lane * 4;
            p[0] += x0; p[1] += x1; p[2] += x2; p[3] += x3;
        }
    }
    __syncthreads();
    for (int i = lane; i < NS * D; i += 64) atomicAdd(he + i, acc[i]);
}

// ---------------------------------------------------------------------------
// BigB[rho=0][d][c] = he[c][d];  BigB[t+1][d][c] = sum_k lin_w[t,d,k]*he[c,k]
// beta[t+1][c] = sum_k lin_b[t,k]*he[c,k]   (beta[0]=0, pre-zeroed)
// ---------------------------------------------------------------------------
__global__ void bigb_copy(const float* __restrict__ he, float* __restrict__ BigB)
{
    int idx = blockIdx.x * 256 + threadIdx.x;
    if (idx < D * NS) {
        int d = idx >> 6, c = idx & 63;
        BigB[idx] = he[(size_t)c * D + d];
    }
}

__global__ __launch_bounds__(256)
void bigb_mm(const float* __restrict__ lin_w, const float* __restrict__ lin_b,
             const float* __restrict__ he, float* __restrict__ BigB,
             float* __restrict__ beta)
{
    int gw = (int)((blockIdx.x * 256 + threadIdx.x) >> 6);
    int lane = threadIdx.x & 63;
    const int totalA = T * D * NS;
    if (gw >= totalA + T * NS) return;
    const float* xrow; const float* hrow; float* outp;
    if (gw < totalA) {
        int t = gw / (D * NS); int rem = gw - t * D * NS;
        int d = rem / NS; int c = rem - d * NS;
        xrow = lin_w + ((size_t)t * D + d) * D;
        hrow = he + (size_t)c * D;
        outp = BigB + ((size_t)(t + 1) * D + d) * NS + c;
    } else {
        int i = gw - totalA; int t = i / NS; int c = i - t * NS;
        xrow = lin_b + (size_t)t * D;
        hrow = he + (size_t)c * D;
        outp = beta + (size_t)(t + 1) * NS + c;
    }
    float4 x = *(const float4*)(xrow + lane * 4);
    float4 h = *(const float4*)(hrow + lane * 4);
    float s = x.x * h.x + x.y * h.y + x.z * h.z + x.w * h.w;
#pragma unroll
    for (int off = 32; off; off >>= 1) s += __shfl_xor(s, off);
    if (lane == 0) *outp = s;
}

// ---------------------------------------------------------------------------
// dots GEMM: feat(Nn x 256) @ BigB(5 x 256 x 64) -> dots(5 x Nn x 64), *1/16 + beta
// tile 64 rows x 320 cols (all 5 rho), acc 4x20/thread, BK=16
// ---------------------------------------------------------------------------
__global__ __launch_bounds__(256)
void dots_gemm(const float* __restrict__ feat, const float* __restrict__ BigB,
               const float* __restrict__ beta, float* __restrict__ dots, int Nn)
{
    __shared__ float As[16][64 + 4];
    __shared__ float Bs[16][320];
    int t = threadIdx.x;
    int tx = t & 15, ty = t >> 4;
    int m0 = blockIdx.x * 64;

    float acc[4][20];
#pragma unroll
    for (int i = 0; i < 4; i++)
#pragma unroll
        for (int j = 0; j < 20; j++) acc[i][j] = 0.f;

    for (int k0 = 0; k0 < D; k0 += 16) {
        {
            int row = t >> 2, c4 = (t & 3) * 4;
            int gm = m0 + row;
            float4 v = make_float4(0.f, 0.f, 0.f, 0.f);
            if (gm < Nn) v = *(const float4*)(feat + (size_t)gm * D + k0 + c4);
            As[c4 + 0][row] = v.x; As[c4 + 1][row] = v.y;
            As[c4 + 2][row] = v.z; As[c4 + 3][row] = v.w;
        }
#pragma unroll
        for (int i = 0; i < 5; i++) {
            int idx4 = t + i * 256;            // 0..1279
            int d = idx4 / 80, col4 = idx4 % 80;
            int rho = col4 >> 4, c4 = (col4 & 15) * 4;
            float4 v = *(const float4*)(BigB + ((size_t)rho * D + k0 + d) * NS + c4);
            *(float4*)&Bs[d][rho * 64 + c4] = v;
        }
        __syncthreads();
#pragma unroll
        for (int kk = 0; kk < 16; kk++) {
            float a[4], b[20];
            *(float4*)&a[0] = *(const float4*)&As[kk][ty * 4];
#pragma unroll
            for (int q = 0; q < 5; q++)
                *(float4*)&b[q * 4] = *(const float4*)&Bs[kk][q * 64 + tx * 4];
#pragma unroll
            for (int i = 0; i < 4; i++)
#pragma unroll
                for (int j = 0; j < 20; j++)
                    acc[i][j] = fmaf(a[i], b[j], acc[i][j]);
        }
        __syncthreads();
    }

#pragma unroll
    for (int i = 0; i < 4; i++) {
        int gm = m0 + ty * 4 + i;
        if (gm >= Nn) continue;
#pragma unroll
        for (int q = 0; q < 5; q++) {
            int c = tx * 4;
            float4 bv = *(const float4*)(beta + q * NS + c);
            float4 o;
            o.x = (acc[i][q * 4 + 0] + bv.x) * 0.0625f;
            o.y = (acc[i][q * 4 + 1] + bv.y) * 0.0625f;
            o.z = (acc[i][q * 4 + 2] + bv.z) * 0.0625f;
            o.w = (acc[i][q * 4 + 3] + bv.w) * 0.0625f;
            *(float4*)(dots + ((size_t)q * Nn + gm) * NS + c) = o;
        }
    }
}

// ---------------------------------------------------------------------------
extern "C" void kernel_launch(void* const* d_in, const int* in_sizes, int n_in,
                              void* d_out, int out_size, void* d_ws, size_t ws_size,
                              hipStream_t stream)
{
    const int*   edge_index = (const int*)d_in[0];
    const float* features   = (const float*)d_in[1];
    const float* lin_w      = (const float*)d_in[2];
    const float* lin_b      = (const float*)d_in[3];
    const float* gcn0_w     = (const float*)d_in[4];
    const float* gcn0_b     = (const float*)d_in[5];
    const float* gcn1_w     = (const float*)d_in[6];
    const float* gcn1_b     = (const float*)d_in[7];
    const float* lin1_w     = (const float*)d_in[8];
    const float* lin1_b     = (const float*)d_in[9];

    int E  = in_sizes[0] / 2;
    int Nn = in_sizes[1] / D;
    int n_total = (T + 1) * Nn;
    int Mrep = T * Nn;
    int colcap = 2 * E + (2 * T + 1) * Nn;

    const int* src = edge_index;
    const int* dst = edge_index + E;

    float* out_H    = (float*)d_out;
    float* out_he   = out_H + (size_t)Nn * NS;
    float* out_dots = out_he + (size_t)NS * D;

    // ---- workspace carve: two big bf16 regions + BigB (~256.3 MB)
    char* ws = (char*)d_ws;
    auto carve = [&](size_t bytes) {
        char* p = ws; ws += (bytes + 255) & ~(size_t)255; return p;
    };
    unsigned short* R1   = (unsigned short*)carve((size_t)n_total * D * 2); // agg0 -> h
    unsigned short* R2   = (unsigned short*)carve((size_t)n_total * D * 2); // transformed -> agg1 -> af2
    float*          BigB = (float*)carve((size_t)(T + 1) * D * NS * 4);
    float*          beta = (float*)carve((size_t)(T + 1) * NS * 4);
    unsigned short* transformed = R2;   // prefix: Mrep*D bf16, dead before agg1

    // ---- small scratch lives in the out_dots region (dead until dots_gemm,
    //      which fully overwrites it at the very end)
    char* sc = (char*)out_dots;
    auto carve2 = [&](size_t bytes) {
        char* p = sc; sc += (bytes + 255) & ~(size_t)255; return p;
    };
    float* tinv   = (float*)carve2((size_t)Mrep * 4);
    int*   best   = (int*)carve2((size_t)E * 4);
    int*   cnt    = (int*)carve2((size_t)n_total * 4);
    int*   rowptr = (int*)carve2((size_t)(n_total + 1) * 4);
    int*   fill   = (int*)carve2((size_t)n_total * 4);
    float* dinv   = (float*)carve2((size_t)n_total * 4);
    int*   aux    = (int*)carve2(1024 * 4);
    int*   auxex  = (int*)carve2(1024 * 4);
    int*   col    = (int*)carve2((size_t)colcap * 4);
    float* val    = (float*)carve2((size_t)colcap * 4);

    // ---- zero the accumulators (ws/out are poisoned before every launch)
    zero_kernel<<<512, 256, 0, stream>>>((uint32*)cnt, n_total);
    zero_kernel<<<512, 256, 0, stream>>>((uint32*)fill, n_total);
    zero_kernel<<<512, 256, 0, stream>>>((uint32*)out_H, (long long)Nn * NS + NS * D);
    zero_kernel<<<1, 256, 0, stream>>>((uint32*)beta, (T + 1) * NS);

    // 1. transformed[t] = feat @ lin_w[t] + lin_b[t]   (bf16 out)
    dim3 g0((Nn + 127) / 128, 2, T);
    gemm_f32_bf16<<<g0, 256, 0, stream>>>(features, lin_w, lin_b, transformed, Nn);

    // 2/3. row norms + per-edge best replica
    tinv_kernel<<<(Mrep + 3) / 4, 256, 0, stream>>>(transformed, tinv, Mrep);
    sim_kernel<<<(E + 3) / 4, 256, 0, stream>>>(src, dst, features, transformed,
                                                tinv, best, E, Nn);

    // 4. CSR build (deg == cnt)
    hist_kernel<<<2048, 256, 0, stream>>>(src, dst, best, cnt, E, Nn);
    dinv_kernel<<<(n_total + 255) / 256, 256, 0, stream>>>(cnt, dinv, n_total);
    int nb = (n_total + 255) / 256;
    scan_sums<<<nb, 256, 0, stream>>>(cnt, aux, n_total);
    scan_aux<<<1, 1024, 0, stream>>>(aux, auxex, nb);
    scan_write<<<nb, 256, 0, stream>>>(cnt, auxex, rowptr, n_total);
    scatter_kernel<<<2048, 256, 0, stream>>>(src, dst, best, rowptr, fill, dinv,
                                             col, val, E, Nn);

    // 5. layer 0: agg0 -> R1; h = agg0@W0+b0 in-place
    agg_kernel<0><<<(n_total + 3) / 4, 256, 0, stream>>>(rowptr, col, val, features,
                                                         transformed, Nn, R1, n_total);
    gemm_bf16_inplace<<<(n_total + 127) / 128, 256, 0, stream>>>(R1, gcn0_w, gcn0_b, n_total);

    // 6. layer 1: agg1 -> R2 (transformed dead); af2 = agg1@W1+b1 in-place
    agg_kernel<1><<<(n_total + 3) / 4, 256, 0, stream>>>(rowptr, col, val, nullptr,
                                                         R1, 0, R2, n_total);
    gemm_bf16_inplace<<<(n_total + 127) / 128, 256, 0, stream>>>(R2, gcn1_w, gcn1_b, n_total);

    // 7. classes + H (GEMM-tiled)
    logits_gemm<<<(n_total + 63) / 64, 256, 0, stream>>>(R2, lin1_w, lin1_b,
                                                         out_H, n_total, Nn);
    // 8. hyperedge features
    he_kernel<<<(Nn + 127) / 128, 64, 0, stream>>>(out_H, R2, out_he, Nn);

    // 9. dots = feat @ [he^T | lin_w[t]@he^T] + beta, scaled (GEMM-tiled)
    bigb_copy<<<(D * NS + 255) / 256, 256, 0, stream>>>(out_he, BigB);
    bigb_mm<<<(T * D * NS + T * NS + 3) / 4, 256, 0, stream>>>(lin_w, lin_b, out_he,
                                                               BigB, beta);
    dots_gemm<<<(Nn + 63) / 64, 256, 0, stream>>>(features, BigB, beta,
                                                  out_dots, Nn);
}

// Round 4
// 1770.006 us; speedup vs baseline: 2.7775x; 1.7302x over previous
//
#include <hip/hip_runtime.h>

#define D 256
#define T 4
#define NS 64

typedef unsigned int uint32;
typedef short s16x8 __attribute__((ext_vector_type(8)));
typedef float f32x4 __attribute__((ext_vector_type(4)));

// ---- bf16 helpers (manual RNE, no API dependence) -------------------------
__device__ __forceinline__ float bflo(uint32 u) { return __uint_as_float(u << 16); }
__device__ __forceinline__ float bfhi(uint32 u) { return __uint_as_float(u & 0xffff0000u); }
__device__ __forceinline__ unsigned short f2bf(float x) {
    uint32 u = __float_as_uint(x);
    u = u + 0x7FFFu + ((u >> 16) & 1u);
    return (unsigned short)(u >> 16);
}
__device__ __forceinline__ uint32 pack2(float a, float b) {
    return (uint32)f2bf(a) | ((uint32)f2bf(b) << 16);
}

// ---------------------------------------------------------------------------
__global__ void zero_kernel(uint32* __restrict__ p, long long n)
{
    long long i = (long long)blockIdx.x * blockDim.x + threadIdx.x;
    long long st = (long long)gridDim.x * blockDim.x;
    for (; i < n; i += st) p[i] = 0u;
}

// ---------------------------------------------------------------------------
// fp32 -> bf16 bulk convert (features)
// ---------------------------------------------------------------------------
__global__ void f2bf_kernel(const float* __restrict__ in, unsigned short* __restrict__ out,
                            long long n8)
{
    long long i = (long long)blockIdx.x * blockDim.x + threadIdx.x;
    long long st = (long long)gridDim.x * blockDim.x;
    for (; i < n8; i += st) {
        float4 a = *(const float4*)(in + i * 8);
        float4 b = *(const float4*)(in + i * 8 + 4);
        uint4 o;
        o.x = pack2(a.x, a.y); o.y = pack2(a.z, a.w);
        o.z = pack2(b.x, b.y); o.w = pack2(b.z, b.w);
        *(uint4*)(out + i * 8) = o;
    }
}

// ---------------------------------------------------------------------------
// Convert 6 weight matrices (gcn0, gcn1, lin_w[0..3]) fp32 256x256 (row=k_in,
// col=k_out) into MFMA B-fragment-linear bf16:
// offset(nt,ks,lane,j) = ((nt*8+ks)*64 + lane)*8 + j
// where lane = quad*16 + n15, k = ks*32 + quad*8 + j, n = nt*16 + n15
// ---------------------------------------------------------------------------
__global__ void wfrag_kernel(const float* __restrict__ g0, const float* __restrict__ g1,
                             const float* __restrict__ lw, unsigned short* __restrict__ out)
{
    int o = blockIdx.x * 256 + threadIdx.x;   // 0..65535
    int mat = blockIdx.y;
    const float* W = (mat == 0) ? g0 : (mat == 1) ? g1 : (lw + (size_t)(mat - 2) * 65536);
    int j = o & 7, lane = (o >> 3) & 63, ks = (o >> 9) & 7, nt = o >> 12;
    int n15 = lane & 15, quad = lane >> 4;
    int k = ks * 32 + quad * 8 + j;
    int n = nt * 16 + n15;
    out[(size_t)mat * 65536 + o] = f2bf(W[(size_t)k * 256 + n]);
}

// ---------------------------------------------------------------------------
// MFMA GEMM: Cout(bf16, Mx256) = A(bf16, Mx256) @ W(bf16 frag-linear) + bias.
// Persistent 64-row stripes; B entirely in registers (wave owns 64 cols);
// A staged row-major in LDS (pad 264 -> 2-way max). In-place safe (stripe is
// fully read into LDS before its rows are written).
// ---------------------------------------------------------------------------
__global__ __launch_bounds__(256, 2)
void gemm_mfma(const unsigned short* __restrict__ A,
               const unsigned short* __restrict__ Wfrag,
               const float* __restrict__ bias,
               unsigned short* __restrict__ Cout,
               int M, int nStripes)
{
    __shared__ unsigned short Asm[64 * 264];
    int t = threadIdx.x, w = t >> 6, lane = t & 63;
    int n15 = lane & 15, quad = lane >> 4;

    // preload all B fragments for this wave's 64 columns: 128 VGPRs
    s16x8 bfr[4][8];
#pragma unroll
    for (int nt = 0; nt < 4; nt++)
#pragma unroll
        for (int ks = 0; ks < 8; ks++)
            bfr[nt][ks] = *(const s16x8*)(Wfrag +
                (size_t)(((w * 4 + nt) * 8 + ks) * 64 + lane) * 8);

    float bcol[4];
#pragma unroll
    for (int nt = 0; nt < 4; nt++) bcol[nt] = bias[(w * 4 + nt) * 16 + n15];

    for (int s = blockIdx.x; s < nStripes; s += gridDim.x) {
        int m0 = s * 64;
        __syncthreads();   // previous stripe's LDS readers are done
#pragma unroll
        for (int i = 0; i < 8; i++) {
            int idx = i * 256 + t;
            int m = idx >> 5, kc = (idx & 31) * 8;
            int gm = m0 + m;
            uint4 v = make_uint4(0u, 0u, 0u, 0u);
            if (gm < M) v = *(const uint4*)(A + (size_t)gm * 256 + kc);
            *(uint4*)(Asm + m * 264 + kc) = v;
        }
        __syncthreads();

        f32x4 acc[4][4];
#pragma unroll
        for (int rt = 0; rt < 4; rt++)
#pragma unroll
            for (int nt = 0; nt < 4; nt++)
#pragma unroll
                for (int e = 0; e < 4; e++) acc[rt][nt][e] = 0.f;

#pragma unroll
        for (int rt = 0; rt < 4; rt++) {
            int abase = (rt * 16 + n15) * 264 + quad * 8;
#pragma unroll
            for (int ks = 0; ks < 8; ks++) {
                s16x8 a = *(const s16x8*)(Asm + abase + ks * 32);
#pragma unroll
                for (int nt = 0; nt < 4; nt++)
                    acc[rt][nt] = __builtin_amdgcn_mfma_f32_16x16x32_bf16(
                        a, bfr[nt][ks], acc[rt][nt], 0, 0, 0);
            }
        }

        // epilogue: + bias, bf16 pack, in-place store
#pragma unroll
        for (int rt = 0; rt < 4; rt++) {
            int row0 = m0 + rt * 16 + quad * 4;
#pragma unroll
            for (int nt = 0; nt < 4; nt++) {
                int colp = (w * 4 + nt) * 16 + n15;
#pragma unroll
                for (int r = 0; r < 4; r++) {
                    int gr = row0 + r;
                    if (gr < M)
                        Cout[(size_t)gr * 256 + colp] = f2bf(acc[rt][nt][r] + bcol[nt]);
                }
            }
        }
    }
}

// ---------------------------------------------------------------------------
__global__ __launch_bounds__(256)
void tinv_kernel(const unsigned short* __restrict__ tr, float* __restrict__ tinv, int rows)
{
    int wave = threadIdx.x >> 6, lane = threadIdx.x & 63;
    int r = blockIdx.x * 4 + wave;
    if (r >= rows) return;
    uint2 q = *(const uint2*)(tr + (size_t)r * D + lane * 4);
    float a = bflo(q.x), b = bfhi(q.x), c = bflo(q.y), d = bfhi(q.y);
    float s = a * a + b * b + c * c + d * d;
#pragma unroll
    for (int off = 32; off; off >>= 1) s += __shfl_xor(s, off);
    if (lane == 0) tinv[r] = 1.f / fmaxf(sqrtf(s), 1e-8f);
}

// ---------------------------------------------------------------------------
__global__ __launch_bounds__(256)
void sim_kernel(const int* __restrict__ src, const int* __restrict__ dst,
                const float* __restrict__ feat, const unsigned short* __restrict__ tr,
                const float* __restrict__ tinv, int* __restrict__ best, int E, int Nn)
{
    int wave = threadIdx.x >> 6, lane = threadIdx.x & 63;
    int e = blockIdx.x * 4 + wave;
    if (e >= E) return;
    int s = src[e], d = dst[e];
    float4 f4 = *(const float4*)(feat + (size_t)s * D + lane * 4);
    float p[T];
#pragma unroll
    for (int i = 0; i < T; i++) {
        uint2 q = *(const uint2*)(tr + ((size_t)i * Nn + d) * D + lane * 4);
        p[i] = f4.x * bflo(q.x) + f4.y * bfhi(q.x) + f4.z * bflo(q.y) + f4.w * bfhi(q.y);
    }
#pragma unroll
    for (int off = 32; off; off >>= 1) {
#pragma unroll
        for (int i = 0; i < T; i++) p[i] += __shfl_xor(p[i], off);
    }
    if (lane == 0) {
        float bv = -1e30f; int bi = 0;
#pragma unroll
        for (int i = 0; i < T; i++) {
            float v = p[i] * tinv[(size_t)i * Nn + d];
            if (v > bv) { bv = v; bi = i; }   // strict >: first-index ties like jnp.argmax
        }
        best[e] = bi;
    }
}

// ---------------------------------------------------------------------------
// unified edge list: [0,E) copy1, [E,2E) rewired copy, [2E,2E+T*N) identity,
// then n_total self loops. keep == (reference weight != 0).
// ---------------------------------------------------------------------------
__device__ __forceinline__ void decode_edge(int e, const int* __restrict__ src,
                                            const int* __restrict__ dst,
                                            const int* __restrict__ best,
                                            int E, int Nn, int& s, int& d, bool& keep)
{
    if (e < E) { s = src[e]; d = dst[e]; keep = (s != d); }
    else if (e < 2 * E) {
        int k = e - E; s = src[k]; d = dst[k] + best[k] * Nn; keep = (s != d);
    } else if (e < 2 * E + T * Nn) {
        int k = e - 2 * E; int i = k / Nn; int n = k - i * Nn;
        s = n; d = n + i * Nn; keep = (i != 0);
    } else {
        int v = e - (2 * E + T * Nn); s = v; d = v; keep = true;
    }
}

__global__ void hist_kernel(const int* __restrict__ src, const int* __restrict__ dst,
                            const int* __restrict__ best, int* __restrict__ cnt,
                            int E, int Nn)
{
    int total = 2 * E + (2 * T + 1) * Nn;
    for (int e = blockIdx.x * blockDim.x + threadIdx.x; e < total;
         e += gridDim.x * blockDim.x) {
        int s, d; bool keep;
        decode_edge(e, src, dst, best, E, Nn, s, d, keep);
        if (keep) atomicAdd(cnt + d, 1);
    }
}

__global__ void dinv_kernel(const int* __restrict__ cnt, float* __restrict__ dinv, int n)
{
    int v = blockIdx.x * blockDim.x + threadIdx.x;
    if (v < n) dinv[v] = (cnt[v] > 0) ? rsqrtf((float)cnt[v]) : 0.f;
}

__global__ void scan_sums(const int* __restrict__ cnt, int* __restrict__ aux, int n)
{
    __shared__ int sd[256];
    int idx = blockIdx.x * 256 + threadIdx.x;
    sd[threadIdx.x] = (idx < n) ? cnt[idx] : 0;
    __syncthreads();
    for (int off = 128; off; off >>= 1) {
        if (threadIdx.x < off) sd[threadIdx.x] += sd[threadIdx.x + off];
        __syncthreads();
    }
    if (threadIdx.x == 0) aux[blockIdx.x] = sd[0];
}

__global__ void scan_aux(const int* __restrict__ aux, int* __restrict__ auxex, int nb)
{
    __shared__ int sd[1024];
    int t = threadIdx.x;
    int v = (t < nb) ? aux[t] : 0;
    sd[t] = v;
    __syncthreads();
    for (int off = 1; off < 1024; off <<= 1) {
        int x = (t >= off) ? sd[t - off] : 0;
        __syncthreads();
        sd[t] += x;
        __syncthreads();
    }
    if (t < nb) auxex[t] = sd[t] - v;
}

__global__ void scan_write(const int* __restrict__ cnt, const int* __restrict__ auxex,
                           int* __restrict__ rowptr, int n)
{
    __shared__ int sd[256];
    int t = threadIdx.x;
    int idx = blockIdx.x * 256 + t;
    int v = (idx < n) ? cnt[idx] : 0;
    sd[t] = v;
    __syncthreads();
    for (int off = 1; off < 256; off <<= 1) {
        int x = (t >= off) ? sd[t - off] : 0;
        __syncthreads();
        sd[t] += x;
        __syncthreads();
    }
    if (idx < n) {
        int rp = auxex[blockIdx.x] + sd[t] - v;
        rowptr[idx] = rp;
        if (idx == n - 1) rowptr[n] = rp + v;
    }
}

__global__ void scatter_kernel(const int* __restrict__ src, const int* __restrict__ dst,
                               const int* __restrict__ best, const int* __restrict__ rowptr,
                               int* __restrict__ fill, const float* __restrict__ dinv,
                               int* __restrict__ col, float* __restrict__ val,
                               int E, int Nn)
{
    int total = 2 * E + (2 * T + 1) * Nn;
    for (int e = blockIdx.x * blockDim.x + threadIdx.x; e < total;
         e += gridDim.x * blockDim.x) {
        int s, d; bool keep;
        decode_edge(e, src, dst, best, E, Nn, s, d, keep);
        if (keep) {
            int pos = rowptr[d] + atomicAdd(fill + d, 1);
            col[pos] = s;
            val[pos] = dinv[s] * dinv[d];
        }
    }
}

// ---------------------------------------------------------------------------
// aggregate-first: out[v] = sum_j val[j] * relu(x[col[j]])   (bf16 out, no bias)
// MODE 0: x = concat(feat fp32 [0,split), transformed bf16)   MODE 1: x = bf16 buf
// ---------------------------------------------------------------------------
template<int MODE>
__global__ __launch_bounds__(256)
void agg_kernel(const int* __restrict__ rowptr, const int* __restrict__ col,
                const float* __restrict__ val, const float* __restrict__ featf,
                const unsigned short* __restrict__ xb, int split,
                unsigned short* __restrict__ outb, int n_total)
{
    int wave = threadIdx.x >> 6, lane = threadIdx.x & 63;
    int v = blockIdx.x * 4 + wave;
    if (v >= n_total) return;
    int j0 = rowptr[v], j1 = rowptr[v + 1];
    float ax = 0.f, ay = 0.f, az = 0.f, aw = 0.f;
    for (int j = j0; j < j1; j++) {
        int s = col[j];
        float w = val[j];
        float x0, x1, x2, x3;
        if (MODE == 0 && s < split) {
            float4 f = *(const float4*)(featf + (size_t)s * D + lane * 4);
            x0 = f.x; x1 = f.y; x2 = f.z; x3 = f.w;
        } else {
            const unsigned short* p = (MODE == 0) ? (xb + (size_t)(s - split) * D)
                                                  : (xb + (size_t)s * D);
            uint2 q = *(const uint2*)(p + lane * 4);
            x0 = bflo(q.x); x1 = bfhi(q.x); x2 = bflo(q.y); x3 = bfhi(q.y);
        }
        ax = fmaf(w, fmaxf(x0, 0.f), ax);
        ay = fmaf(w, fmaxf(x1, 0.f), ay);
        az = fmaf(w, fmaxf(x2, 0.f), az);
        aw = fmaf(w, fmaxf(x3, 0.f), aw);
    }
    uint2 o; o.x = pack2(ax, ay); o.y = pack2(az, aw);
    *(uint2*)(outb + (size_t)v * D + lane * 4) = o;
}

// ---------------------------------------------------------------------------
// GEMM-style logits + argmax: tile 64 rows x 64 cols, acc 4x4/thread.
// ---------------------------------------------------------------------------
__global__ __launch_bounds__(256)
void logits_gemm(const unsigned short* __restrict__ af2, const float* __restrict__ Wl,
                 const float* __restrict__ bl, float* __restrict__ H, int Mrows, int Nn)
{
    __shared__ float As[16][64 + 4];
    __shared__ float Bs[16][64];
    __shared__ float Ls[64][68];
    int t = threadIdx.x;
    int tx = t & 15, ty = t >> 4;
    int m0 = blockIdx.x * 64;

    float acc[4][4];
#pragma unroll
    for (int i = 0; i < 4; i++)
#pragma unroll
        for (int j = 0; j < 4; j++) acc[i][j] = 0.f;

    for (int k0 = 0; k0 < D; k0 += 16) {
        {
            int row = t >> 2, c4 = (t & 3) * 4;
            int gm = m0 + row;
            float x0 = 0.f, x1 = 0.f, x2 = 0.f, x3 = 0.f;
            if (gm < Mrows) {
                uint2 q = *(const uint2*)(af2 + (size_t)gm * D + k0 + c4);
                x0 = fmaxf(bflo(q.x), 0.f); x1 = fmaxf(bfhi(q.x), 0.f);
                x2 = fmaxf(bflo(q.y), 0.f); x3 = fmaxf(bfhi(q.y), 0.f);
            }
            As[c4 + 0][row] = x0; As[c4 + 1][row] = x1;
            As[c4 + 2][row] = x2; As[c4 + 3][row] = x3;
        }
        {
            int d = t >> 4, c4 = (t & 15) * 4;
            *(float4*)&Bs[d][c4] = *(const float4*)(Wl + (size_t)(k0 + d) * NS + c4);
        }
        __syncthreads();
#pragma unroll
        for (int kk = 0; kk < 16; kk++) {
            float a[4], b[4];
            *(float4*)&a[0] = *(const float4*)&As[kk][ty * 4];
            *(float4*)&b[0] = *(const float4*)&Bs[kk][tx * 4];
#pragma unroll
            for (int i = 0; i < 4; i++)
#pragma unroll
                for (int j = 0; j < 4; j++)
                    acc[i][j] = fmaf(a[i], b[j], acc[i][j]);
        }
        __syncthreads();
    }

    float4 bb = *(const float4*)(bl + tx * 4);
#pragma unroll
    for (int i = 0; i < 4; i++) {
        float4 v;
        v.x = acc[i][0] + bb.x; v.y = acc[i][1] + bb.y;
        v.z = acc[i][2] + bb.z; v.w = acc[i][3] + bb.w;
        *(float4*)&Ls[ty * 4 + i][tx * 4] = v;
    }
    __syncthreads();
    if (t < 64) {
        int grow = m0 + t;
        if (grow < Mrows) {
            float bv = -3.4e38f; int bi = 0;
#pragma unroll
            for (int k4 = 0; k4 < 16; k4++) {
                float4 v = *(const float4*)&Ls[t][k4 * 4];
                if (v.x > bv) { bv = v.x; bi = k4 * 4 + 0; }
                if (v.y > bv) { bv = v.y; bi = k4 * 4 + 1; }
                if (v.z > bv) { bv = v.z; bi = k4 * 4 + 2; }
                if (v.w > bv) { bv = v.w; bi = k4 * 4 + 3; }
            }
            atomicAdd(H + (size_t)(grow % Nn) * NS + bi, 1.0f);
        }
    }
}

// ---------------------------------------------------------------------------
// he[c] = sum_{n: H[n,c]>0} af2[n]   (one wave per block, 128 nodes/block)
// ---------------------------------------------------------------------------
__global__ __launch_bounds__(64)
void he_kernel(const float* __restrict__ H, const unsigned short* __restrict__ af2,
               float* __restrict__ he, int Nn)
{
    __shared__ float acc[NS * D];   // 64 KiB exactly
    int lane = threadIdx.x;
    for (int i = lane * 4; i < NS * D; i += 256)
        *(float4*)(acc + i) = make_float4(0.f, 0.f, 0.f, 0.f);
    __syncthreads();
    int n0 = blockIdx.x * 128;
    int n1 = min(n0 + 128, Nn);
    for (int n = n0; n < n1; n++) {
        float hv = H[(size_t)n * NS + lane];
        unsigned long long m = __ballot(hv > 0.f);
        if (!m) continue;
        uint2 q = *(const uint2*)(af2 + (size_t)n * D + lane * 4);
        float x0 = bflo(q.x), x1 = bfhi(q.x), x2 = bflo(q.y), x3 = bfhi(q.y);
        while (m) {
            int c = __ffsll(m) - 1;
            m &= m - 1;
            float* p = acc + (size_t)c * D + lane * 4;
            p[0] += x0; p[1] += x1; p[2] += x2; p[3] += x3;
        }
    }
    __syncthreads();
    for (int i = lane; i < NS * D; i += 64) atomicAdd(he + i, acc[i]);
}

// ---------------------------------------------------------------------------
__global__ void bigb_copy(const float* __restrict__ he, float* __restrict__ BigB)
{
    int idx = blockIdx.x * 256 + threadIdx.x;
    if (idx < D * NS) {
        int d = idx >> 6, c = idx & 63;
        BigB[idx] = he[(size_t)c * D + d];
    }
}

__global__ __launch_bounds__(256)
void bigb_mm(const float* __restrict__ lin_w, const float* __restrict__ lin_b,
             const float* __restrict__ he, float* __restrict__ BigB,
             float* __restrict__ beta)
{
    int gw = (int)((blockIdx.x * 256 + threadIdx.x) >> 6);
    int lane = threadIdx.x & 63;
    const int totalA = T * D * NS;
    if (gw >= totalA + T * NS) return;
    const float* xrow; const float* hrow; float* outp;
    if (gw < totalA) {
        int t = gw / (D * NS); int rem = gw - t * D * NS;
        int d = rem / NS; int c = rem - d * NS;
        xrow = lin_w + ((size_t)t * D + d) * D;
        hrow = he + (size_t)c * D;
        outp = BigB + ((size_t)(t + 1) * D + d) * NS + c;
    } else {
        int i = gw - totalA; int t = i / NS; int c = i - t * NS;
        xrow = lin_b + (size_t)t * D;
        hrow = he + (size_t)c * D;
        outp = beta + (size_t)(t + 1) * NS + c;
    }
    float4 x = *(const float4*)(xrow + lane * 4);
    float4 h = *(const float4*)(hrow + lane * 4);
    float s = x.x * h.x + x.y * h.y + x.z * h.z + x.w * h.w;
#pragma unroll
    for (int off = 32; off; off >>= 1) s += __shfl_xor(s, off);
    if (lane == 0) *outp = s;
}

// ---------------------------------------------------------------------------
// dots GEMM: feat(Nn x 256) @ BigB(5 x 256 x 64) -> dots(5 x Nn x 64)
// ---------------------------------------------------------------------------
__global__ __launch_bounds__(256)
void dots_gemm(const float* __restrict__ feat, const float* __restrict__ BigB,
               const float* __restrict__ beta, float* __restrict__ dots, int Nn)
{
    __shared__ float As[16][64 + 4];
    __shared__ float Bs[16][320];
    int t = threadIdx.x;
    int tx = t & 15, ty = t >> 4;
    int m0 = blockIdx.x * 64;

    float acc[4][20];
#pragma unroll
    for (int i = 0; i < 4; i++)
#pragma unroll
        for (int j = 0; j < 20; j++) acc[i][j] = 0.f;

    for (int k0 = 0; k0 < D; k0 += 16) {
        {
            int row = t >> 2, c4 = (t & 3) * 4;
            int gm = m0 + row;
            float4 v = make_float4(0.f, 0.f, 0.f, 0.f);
            if (gm < Nn) v = *(const float4*)(feat + (size_t)gm * D + k0 + c4);
            As[c4 + 0][row] = v.x; As[c4 + 1][row] = v.y;
            As[c4 + 2][row] = v.z; As[c4 + 3][row] = v.w;
        }
#pragma unroll
        for (int i = 0; i < 5; i++) {
            int idx4 = t + i * 256;
            int d = idx4 / 80, col4 = idx4 % 80;
            int rho = col4 >> 4, c4 = (col4 & 15) * 4;
            float4 v = *(const float4*)(BigB + ((size_t)rho * D + k0 + d) * NS + c4);
            *(float4*)&Bs[d][rho * 64 + c4] = v;
        }
        __syncthreads();
#pragma unroll
        for (int kk = 0; kk < 16; kk++) {
            float a[4], b[20];
            *(float4*)&a[0] = *(const float4*)&As[kk][ty * 4];
#pragma unroll
            for (int q = 0; q < 5; q++)
                *(float4*)&b[q * 4] = *(const float4*)&Bs[kk][q * 64 + tx * 4];
#pragma unroll
            for (int i = 0; i < 4; i++)
#pragma unroll
                for (int j = 0; j < 20; j++)
                    acc[i][j] = fmaf(a[i], b[j], acc[i][j]);
        }
        __syncthreads();
    }

#pragma unroll
    for (int i = 0; i < 4; i++) {
        int gm = m0 + ty * 4 + i;
        if (gm >= Nn) continue;
#pragma unroll
        for (int q = 0; q < 5; q++) {
            int c = tx * 4;
            float4 bv = *(const float4*)(beta + q * NS + c);
            float4 o;
            o.x = (acc[i][q * 4 + 0] + bv.x) * 0.0625f;
            o.y = (acc[i][q * 4 + 1] + bv.y) * 0.0625f;
            o.z = (acc[i][q * 4 + 2] + bv.z) * 0.0625f;
            o.w = (acc[i][q * 4 + 3] + bv.w) * 0.0625f;
            *(float4*)(dots + ((size_t)q * Nn + gm) * NS + c) = o;
        }
    }
}

// ---------------------------------------------------------------------------
extern "C" void kernel_launch(void* const* d_in, const int* in_sizes, int n_in,
                              void* d_out, int out_size, void* d_ws, size_t ws_size,
                              hipStream_t stream)
{
    const int*   edge_index = (const int*)d_in[0];
    const float* features   = (const float*)d_in[1];
    const float* lin_w      = (const float*)d_in[2];
    const float* lin_b      = (const float*)d_in[3];
    const float* gcn0_w     = (const float*)d_in[4];
    const float* gcn0_b     = (const float*)d_in[5];
    const float* gcn1_w     = (const float*)d_in[6];
    const float* gcn1_b     = (const float*)d_in[7];
    const float* lin1_w     = (const float*)d_in[8];
    const float* lin1_b     = (const float*)d_in[9];

    int E  = in_sizes[0] / 2;
    int Nn = in_sizes[1] / D;
    int n_total = (T + 1) * Nn;
    int Mrep = T * Nn;
    int colcap = 2 * E + (2 * T + 1) * Nn;

    const int* src = edge_index;
    const int* dst = edge_index + E;

    float* out_H    = (float*)d_out;
    float* out_he   = out_H + (size_t)Nn * NS;
    float* out_dots = out_he + (size_t)NS * D;

    // ---- workspace carve: two big bf16 regions + BigB (~256.3 MB)
    char* ws = (char*)d_ws;
    auto carve = [&](size_t bytes) {
        char* p = ws; ws += (bytes + 255) & ~(size_t)255; return p;
    };
    unsigned short* R1   = (unsigned short*)carve((size_t)n_total * D * 2); // agg0 -> h
    unsigned short* R2   = (unsigned short*)carve((size_t)n_total * D * 2); // transformed -> agg1 -> af2
    float*          BigB = (float*)carve((size_t)(T + 1) * D * NS * 4);
    float*          beta = (float*)carve((size_t)(T + 1) * NS * 4);
    unsigned short* transformed = R2;   // prefix: Mrep*D bf16, dead before agg1

    // ---- small scratch in the out_dots region (dead until dots_gemm)
    char* sc = (char*)out_dots;
    auto carve2 = [&](size_t bytes) {
        char* p = sc; sc += (bytes + 255) & ~(size_t)255; return p;
    };
    float* tinv   = (float*)carve2((size_t)Mrep * 4);
    int*   best   = (int*)carve2((size_t)E * 4);
    int*   cnt    = (int*)carve2((size_t)n_total * 4);
    int*   rowptr = (int*)carve2((size_t)(n_total + 1) * 4);
    int*   fill   = (int*)carve2((size_t)n_total * 4);
    float* dinv   = (float*)carve2((size_t)n_total * 4);
    int*   aux    = (int*)carve2(1024 * 4);
    int*   auxex  = (int*)carve2(1024 * 4);
    int*   col    = (int*)carve2((size_t)colcap * 4);
    float* val    = (float*)carve2((size_t)colcap * 4);
    unsigned short* featb  = (unsigned short*)carve2((size_t)Nn * D * 2);   // bf16 features
    unsigned short* Wfrags = (unsigned short*)carve2((size_t)6 * 65536 * 2); // frag-linear weights

    // ---- zero the accumulators
    zero_kernel<<<512, 256, 0, stream>>>((uint32*)cnt, n_total);
    zero_kernel<<<512, 256, 0, stream>>>((uint32*)fill, n_total);
    zero_kernel<<<512, 256, 0, stream>>>((uint32*)out_H, (long long)Nn * NS + NS * D);
    zero_kernel<<<1, 256, 0, stream>>>((uint32*)beta, (T + 1) * NS);

    // 0. weight/feature conversions for MFMA
    wfrag_kernel<<<dim3(256, 6), 256, 0, stream>>>(gcn0_w, gcn1_w, lin_w, Wfrags);
    f2bf_kernel<<<2048, 256, 0, stream>>>(features, featb, (long long)Nn * D / 8);

    // 1. transformed[z] = featb @ lin_w[z] + lin_b[z]   (MFMA, bf16 out)
    int strN = (Nn + 63) / 64;
    for (int z = 0; z < T; z++)
        gemm_mfma<<<512, 256, 0, stream>>>(featb, Wfrags + (size_t)(2 + z) * 65536,
                                           lin_b + (size_t)z * D,
                                           transformed + (size_t)z * Nn * D, Nn, strN);

    // 2/3. row norms + per-edge best replica
    tinv_kernel<<<(Mrep + 3) / 4, 256, 0, stream>>>(transformed, tinv, Mrep);
    sim_kernel<<<(E + 3) / 4, 256, 0, stream>>>(src, dst, features, transformed,
                                                tinv, best, E, Nn);

    // 4. CSR build (deg == cnt)
    hist_kernel<<<2048, 256, 0, stream>>>(src, dst, best, cnt, E, Nn);
    dinv_kernel<<<(n_total + 255) / 256, 256, 0, stream>>>(cnt, dinv, n_total);
    int nb = (n_total + 255) / 256;
    scan_sums<<<nb, 256, 0, stream>>>(cnt, aux, n_total);
    scan_aux<<<1, 1024, 0, stream>>>(aux, auxex, nb);
    scan_write<<<nb, 256, 0, stream>>>(cnt, auxex, rowptr, n_total);
    scatter_kernel<<<2048, 256, 0, stream>>>(src, dst, best, rowptr, fill, dinv,
                                             col, val, E, Nn);

    // 5. layer 0: agg0 -> R1; h = agg0@W0+b0 (MFMA, in-place)
    int strT = (n_total + 63) / 64;
    agg_kernel<0><<<(n_total + 3) / 4, 256, 0, stream>>>(rowptr, col, val, features,
                                                         transformed, Nn, R1, n_total);
    gemm_mfma<<<512, 256, 0, stream>>>(R1, Wfrags, gcn0_b, R1, n_total, strT);

    // 6. layer 1: agg1 -> R2 (transformed dead); af2 = agg1@W1+b1 (MFMA, in-place)
    agg_kernel<1><<<(n_total + 3) / 4, 256, 0, stream>>>(rowptr, col, val, nullptr,
                                                         R1, 0, R2, n_total);
    gemm_mfma<<<512, 256, 0, stream>>>(R2, Wfrags + 65536, gcn1_b, R2, n_total, strT);

    // 7. classes + H (GEMM-tiled)
    logits_gemm<<<(n_total + 63) / 64, 256, 0, stream>>>(R2, lin1_w, lin1_b,
                                                         out_H, n_total, Nn);
    // 8. hyperedge features
    he_kernel<<<(Nn + 127) / 128, 64, 0, stream>>>(out_H, R2, out_he, Nn);

    // 9. dots = feat @ [he^T | lin_w[t]@he^T] + beta, scaled (GEMM-tiled)
    bigb_copy<<<(D * NS + 255) / 256, 256, 0, stream>>>(out_he, BigB);
    bigb_mm<<<(T * D * NS + T * NS + 3) / 4, 256, 0, stream>>>(lin_w, lin_b, out_he,
                                                               BigB, beta);
    dots_gemm<<<(Nn + 63) / 64, 256, 0, stream>>>(features, BigB, beta,
                                                  out_dots, Nn);
}

// Round 5
// 1428.699 us; speedup vs baseline: 3.4411x; 1.2389x over previous
//
#include <hip/hip_runtime.h>

#define D 256
#define T 4
#define NS 64

typedef unsigned int uint32;
typedef short s16x8 __attribute__((ext_vector_type(8)));
typedef float f32x4 __attribute__((ext_vector_type(4)));

// ---- bf16 helpers (manual RNE) --------------------------------------------
__device__ __forceinline__ float bflo(uint32 u) { return __uint_as_float(u << 16); }
__device__ __forceinline__ float bfhi(uint32 u) { return __uint_as_float(u & 0xffff0000u); }
__device__ __forceinline__ unsigned short f2bf(float x) {
    uint32 u = __float_as_uint(x);
    u = u + 0x7FFFu + ((u >> 16) & 1u);
    return (unsigned short)(u >> 16);
}
__device__ __forceinline__ uint32 pack2(float a, float b) {
    return (uint32)f2bf(a) | ((uint32)f2bf(b) << 16);
}
// relu on 2 packed bf16
__device__ __forceinline__ uint32 relu2(uint32 u) {
    uint32 s = u & 0x80008000u;
    uint32 m = ((s >> 15) ^ 0x00010001u) * 0xFFFFu;
    return u & m;
}

// ---------------------------------------------------------------------------
__global__ void zero_kernel(uint32* __restrict__ p, long long n)
{
    long long i = (long long)blockIdx.x * blockDim.x + threadIdx.x;
    long long st = (long long)gridDim.x * blockDim.x;
    for (; i < n; i += st) p[i] = 0u;
}

__global__ void f2bf_kernel(const float* __restrict__ in, unsigned short* __restrict__ out,
                            long long n8)
{
    long long i = (long long)blockIdx.x * blockDim.x + threadIdx.x;
    long long st = (long long)gridDim.x * blockDim.x;
    for (; i < n8; i += st) {
        float4 a = *(const float4*)(in + i * 8);
        float4 b = *(const float4*)(in + i * 8 + 4);
        uint4 o;
        o.x = pack2(a.x, a.y); o.y = pack2(a.z, a.w);
        o.z = pack2(b.x, b.y); o.w = pack2(b.z, b.w);
        *(uint4*)(out + i * 8) = o;
    }
}

// ---------------------------------------------------------------------------
// 6 weight matrices (gcn0, gcn1, lin_w[0..3]) fp32 256x256 -> B-frag-linear bf16
// ---------------------------------------------------------------------------
__global__ void wfrag_kernel(const float* __restrict__ g0, const float* __restrict__ g1,
                             const float* __restrict__ lw, unsigned short* __restrict__ out)
{
    int o = blockIdx.x * 256 + threadIdx.x;   // 0..65535
    int mat = blockIdx.y;
    const float* W = (mat == 0) ? g0 : (mat == 1) ? g1 : (lw + (size_t)(mat - 2) * 65536);
    int j = o & 7, lane = (o >> 3) & 63, ks = (o >> 9) & 7, nt = o >> 12;
    int n15 = lane & 15, quad = lane >> 4;
    int k = ks * 32 + quad * 8 + j;
    int n = nt * 16 + n15;
    out[(size_t)mat * 65536 + o] = f2bf(W[(size_t)k * 256 + n]);
}

// ---------------------------------------------------------------------------
// MFMA GEMM: C(bf16, Mx256) = A(bf16, Mx256) @ W(bf16 frag-linear) + bias.
// grid (nBlk, Z): z offsets Wfrag/bias/C (batched transformed). In-place safe.
// ---------------------------------------------------------------------------
__global__ __launch_bounds__(256, 2)
void gemm_mfma(const unsigned short* __restrict__ A,
               const unsigned short* __restrict__ Wfrag,
               const float* __restrict__ bias,
               unsigned short* __restrict__ Cout,
               int M, int nStripes)
{
    __shared__ unsigned short Asm[64 * 264];
    int t = threadIdx.x, w = t >> 6, lane = t & 63;
    int n15 = lane & 15, quad = lane >> 4;
    int z = blockIdx.y;
    Wfrag += (size_t)z * 65536;
    bias  += (size_t)z * 256;
    Cout  += (size_t)z * (size_t)M * 256;

    s16x8 bfr[4][8];
#pragma unroll
    for (int nt = 0; nt < 4; nt++)
#pragma unroll
        for (int ks = 0; ks < 8; ks++)
            bfr[nt][ks] = *(const s16x8*)(Wfrag +
                (size_t)(((w * 4 + nt) * 8 + ks) * 64 + lane) * 8);

    float bcol[4];
#pragma unroll
    for (int nt = 0; nt < 4; nt++) bcol[nt] = bias[(w * 4 + nt) * 16 + n15];

    for (int s = blockIdx.x; s < nStripes; s += gridDim.x) {
        int m0 = s * 64;
        __syncthreads();
#pragma unroll
        for (int i = 0; i < 8; i++) {
            int idx = i * 256 + t;
            int m = idx >> 5, kc = (idx & 31) * 8;
            int gm = m0 + m;
            uint4 v = make_uint4(0u, 0u, 0u, 0u);
            if (gm < M) v = *(const uint4*)(A + (size_t)gm * 256 + kc);
            *(uint4*)(Asm + m * 264 + kc) = v;
        }
        __syncthreads();

        f32x4 acc[4][4];
#pragma unroll
        for (int rt = 0; rt < 4; rt++)
#pragma unroll
            for (int nt = 0; nt < 4; nt++)
#pragma unroll
                for (int e = 0; e < 4; e++) acc[rt][nt][e] = 0.f;

#pragma unroll
        for (int rt = 0; rt < 4; rt++) {
            int abase = (rt * 16 + n15) * 264 + quad * 8;
#pragma unroll
            for (int ks = 0; ks < 8; ks++) {
                s16x8 a = *(const s16x8*)(Asm + abase + ks * 32);
#pragma unroll
                for (int nt = 0; nt < 4; nt++)
                    acc[rt][nt] = __builtin_amdgcn_mfma_f32_16x16x32_bf16(
                        a, bfr[nt][ks], acc[rt][nt], 0, 0, 0);
            }
        }

#pragma unroll
        for (int rt = 0; rt < 4; rt++) {
            int row0 = m0 + rt * 16 + quad * 4;
#pragma unroll
            for (int nt = 0; nt < 4; nt++) {
                int colp = (w * 4 + nt) * 16 + n15;
#pragma unroll
                for (int r = 0; r < 4; r++) {
                    int gr = row0 + r;
                    if (gr < M)
                        Cout[(size_t)gr * 256 + colp] = f2bf(acc[rt][nt][r] + bcol[nt]);
                }
            }
        }
    }
}

// ---------------------------------------------------------------------------
__global__ __launch_bounds__(256)
void tinv_kernel(const unsigned short* __restrict__ tr, float* __restrict__ tinv, int rows)
{
    int wave = threadIdx.x >> 6, lane = threadIdx.x & 63;
    int r = blockIdx.x * 4 + wave;
    if (r >= rows) return;
    uint2 q = *(const uint2*)(tr + (size_t)r * D + lane * 4);
    float a = bflo(q.x), b = bfhi(q.x), c = bflo(q.y), d = bfhi(q.y);
    float s = a * a + b * b + c * c + d * d;
#pragma unroll
    for (int off = 32; off; off >>= 1) s += __shfl_xor(s, off);
    if (lane == 0) tinv[r] = 1.f / fmaxf(sqrtf(s), 1e-8f);
}

// ---------------------------------------------------------------------------
// edge counting sort by dst
// ---------------------------------------------------------------------------
__global__ void ehist_kernel(const int* __restrict__ dst, int* __restrict__ ecnt, int E)
{
    for (int e = blockIdx.x * blockDim.x + threadIdx.x; e < E;
         e += gridDim.x * blockDim.x)
        atomicAdd(ecnt + dst[e], 1);
}

__global__ void escatter_kernel(const int* __restrict__ src, const int* __restrict__ dst,
                                const int* __restrict__ eptr, int* __restrict__ efill,
                                uint2* __restrict__ esorted, int E)
{
    for (int e = blockIdx.x * blockDim.x + threadIdx.x; e < E;
         e += gridDim.x * blockDim.x) {
        int d = dst[e];
        int pos = eptr[d] + atomicAdd(efill + d, 1);
        esorted[pos] = make_uint2((uint32)src[e], (uint32)e);
    }
}

// ---------------------------------------------------------------------------
// sim grouped by dst: one wave per node; replica rows loaded once per node,
// only featb[src] gathered per edge.
// ---------------------------------------------------------------------------
__global__ __launch_bounds__(256)
void sim2_kernel(const uint2* __restrict__ esorted, const int* __restrict__ eptr,
                 const unsigned short* __restrict__ featb,
                 const unsigned short* __restrict__ tr, const float* __restrict__ tinv,
                 int* __restrict__ best, int Nn)
{
    int wave = threadIdx.x >> 6, lane = threadIdx.x & 63;
    int d = blockIdx.x * 4 + wave;
    if (d >= Nn) return;
    int j0 = eptr[d], j1 = eptr[d + 1];
    if (j0 >= j1) return;
    float tv[T][4], ti[T];
#pragma unroll
    for (int i = 0; i < T; i++) {
        uint2 q = *(const uint2*)(tr + ((size_t)i * Nn + d) * D + lane * 4);
        tv[i][0] = bflo(q.x); tv[i][1] = bfhi(q.x);
        tv[i][2] = bflo(q.y); tv[i][3] = bfhi(q.y);
        ti[i] = tinv[(size_t)i * Nn + d];
    }
    for (int j = j0; j < j1; j++) {
        uint2 se = esorted[j];
        uint2 f = *(const uint2*)(featb + (size_t)se.x * D + lane * 4);
        float f0 = bflo(f.x), f1 = bfhi(f.x), f2 = bflo(f.y), f3 = bfhi(f.y);
        float p0 = f0 * tv[0][0] + f1 * tv[0][1] + f2 * tv[0][2] + f3 * tv[0][3];
        float p1 = f0 * tv[1][0] + f1 * tv[1][1] + f2 * tv[1][2] + f3 * tv[1][3];
        float p2 = f0 * tv[2][0] + f1 * tv[2][1] + f2 * tv[2][2] + f3 * tv[2][3];
        float p3 = f0 * tv[3][0] + f1 * tv[3][1] + f2 * tv[3][2] + f3 * tv[3][3];
#pragma unroll
        for (int off = 32; off; off >>= 1) {
            p0 += __shfl_xor(p0, off);
            p1 += __shfl_xor(p1, off);
            p2 += __shfl_xor(p2, off);
            p3 += __shfl_xor(p3, off);
        }
        if (lane == 0) {
            float v0 = p0 * ti[0], v1 = p1 * ti[1], v2 = p2 * ti[2], v3 = p3 * ti[3];
            float bv = v0; int bi = 0;
            if (v1 > bv) { bv = v1; bi = 1; }
            if (v2 > bv) { bv = v2; bi = 2; }
            if (v3 > bv) { bv = v3; bi = 3; }
            best[se.y] = bi;
        }
    }
}

// ---------------------------------------------------------------------------
// unified edge list for the big graph
// ---------------------------------------------------------------------------
__device__ __forceinline__ void decode_edge(int e, const int* __restrict__ src,
                                            const int* __restrict__ dst,
                                            const int* __restrict__ best,
                                            int E, int Nn, int& s, int& d, bool& keep)
{
    if (e < E) { s = src[e]; d = dst[e]; keep = (s != d); }
    else if (e < 2 * E) {
        int k = e - E; s = src[k]; d = dst[k] + best[k] * Nn; keep = (s != d);
    } else if (e < 2 * E + T * Nn) {
        int k = e - 2 * E; int i = k / Nn; int n = k - i * Nn;
        s = n; d = n + i * Nn; keep = (i != 0);
    } else {
        int v = e - (2 * E + T * Nn); s = v; d = v; keep = true;
    }
}

__global__ void hist_kernel(const int* __restrict__ src, const int* __restrict__ dst,
                            const int* __restrict__ best, int* __restrict__ cnt,
                            int E, int Nn)
{
    int total = 2 * E + (2 * T + 1) * Nn;
    for (int e = blockIdx.x * blockDim.x + threadIdx.x; e < total;
         e += gridDim.x * blockDim.x) {
        int s, d; bool keep;
        decode_edge(e, src, dst, best, E, Nn, s, d, keep);
        if (keep) atomicAdd(cnt + d, 1);
    }
}

__global__ void dinv_kernel(const int* __restrict__ cnt, float* __restrict__ dinv, int n)
{
    int v = blockIdx.x * blockDim.x + threadIdx.x;
    if (v < n) dinv[v] = (cnt[v] > 0) ? rsqrtf((float)cnt[v]) : 0.f;
}

__global__ void scan_sums(const int* __restrict__ cnt, int* __restrict__ aux, int n)
{
    __shared__ int sd[256];
    int idx = blockIdx.x * 256 + threadIdx.x;
    sd[threadIdx.x] = (idx < n) ? cnt[idx] : 0;
    __syncthreads();
    for (int off = 128; off; off >>= 1) {
        if (threadIdx.x < off) sd[threadIdx.x] += sd[threadIdx.x + off];
        __syncthreads();
    }
    if (threadIdx.x == 0) aux[blockIdx.x] = sd[0];
}

__global__ void scan_aux(const int* __restrict__ aux, int* __restrict__ auxex, int nb)
{
    __shared__ int sd[1024];
    int t = threadIdx.x;
    int v = (t < nb) ? aux[t] : 0;
    sd[t] = v;
    __syncthreads();
    for (int off = 1; off < 1024; off <<= 1) {
        int x = (t >= off) ? sd[t - off] : 0;
        __syncthreads();
        sd[t] += x;
        __syncthreads();
    }
    if (t < nb) auxex[t] = sd[t] - v;
}

__global__ void scan_write(const int* __restrict__ cnt, const int* __restrict__ auxex,
                           int* __restrict__ rowptr, int n)
{
    __shared__ int sd[256];
    int t = threadIdx.x;
    int idx = blockIdx.x * 256 + t;
    int v = (idx < n) ? cnt[idx] : 0;
    sd[t] = v;
    __syncthreads();
    for (int off = 1; off < 256; off <<= 1) {
        int x = (t >= off) ? sd[t - off] : 0;
        __syncthreads();
        sd[t] += x;
        __syncthreads();
    }
    if (idx < n) {
        int rp = auxex[blockIdx.x] + sd[t] - v;
        rowptr[idx] = rp;
        if (idx == n - 1) rowptr[n] = rp + v;
    }
}

__global__ void scatter_kernel(const int* __restrict__ src, const int* __restrict__ dst,
                               const int* __restrict__ best, const int* __restrict__ rowptr,
                               int* __restrict__ fill, const float* __restrict__ dinv,
                               int* __restrict__ col, float* __restrict__ val,
                               int E, int Nn)
{
    int total = 2 * E + (2 * T + 1) * Nn;
    for (int e = blockIdx.x * blockDim.x + threadIdx.x; e < total;
         e += gridDim.x * blockDim.x) {
        int s, d; bool keep;
        decode_edge(e, src, dst, best, E, Nn, s, d, keep);
        if (keep) {
            int pos = rowptr[d] + atomicAdd(fill + d, 1);
            col[pos] = s;
            val[pos] = dinv[s] * dinv[d];
        }
    }
}

// ---------------------------------------------------------------------------
// aggregate-first: out[v] = sum_j val[j]*relu(x[col[j]]), x bf16 split across
// xa [0,split) / xb [split,...). unroll x2 for MLP (two gathers in flight).
// ---------------------------------------------------------------------------
__global__ __launch_bounds__(256)
void agg_kernel(const int* __restrict__ rowptr, const int* __restrict__ col,
                const float* __restrict__ val,
                const unsigned short* __restrict__ xa,
                const unsigned short* __restrict__ xb, int split,
                unsigned short* __restrict__ outb, int n_total)
{
    int wave = threadIdx.x >> 6, lane = threadIdx.x & 63;
    int v = blockIdx.x * 4 + wave;
    if (v >= n_total) return;
    int j0 = rowptr[v], j1 = rowptr[v + 1];
    float ax = 0.f, ay = 0.f, az = 0.f, aw = 0.f;
    int j = j0;
    for (; j + 2 <= j1; j += 2) {
        int s0 = col[j], s1 = col[j + 1];
        float w0 = val[j], w1 = val[j + 1];
        const unsigned short* p0 = (s0 < split) ? (xa + (size_t)s0 * D)
                                                : (xb + (size_t)(s0 - split) * D);
        const unsigned short* p1 = (s1 < split) ? (xa + (size_t)s1 * D)
                                                : (xb + (size_t)(s1 - split) * D);
        uint2 q0 = *(const uint2*)(p0 + lane * 4);
        uint2 q1 = *(const uint2*)(p1 + lane * 4);
        q0.x = relu2(q0.x); q0.y = relu2(q0.y);
        q1.x = relu2(q1.x); q1.y = relu2(q1.y);
        ax = fmaf(w0, bflo(q0.x), ax); ay = fmaf(w0, bfhi(q0.x), ay);
        az = fmaf(w0, bflo(q0.y), az); aw = fmaf(w0, bfhi(q0.y), aw);
        ax = fmaf(w1, bflo(q1.x), ax); ay = fmaf(w1, bfhi(q1.x), ay);
        az = fmaf(w1, bflo(q1.y), az); aw = fmaf(w1, bfhi(q1.y), aw);
    }
    if (j < j1) {
        int s0 = col[j];
        float w0 = val[j];
        const unsigned short* p0 = (s0 < split) ? (xa + (size_t)s0 * D)
                                                : (xb + (size_t)(s0 - split) * D);
        uint2 q0 = *(const uint2*)(p0 + lane * 4);
        q0.x = relu2(q0.x); q0.y = relu2(q0.y);
        ax = fmaf(w0, bflo(q0.x), ax); ay = fmaf(w0, bfhi(q0.x), ay);
        az = fmaf(w0, bflo(q0.y), az); aw = fmaf(w0, bfhi(q0.y), aw);
    }
    uint2 o; o.x = pack2(ax, ay); o.y = pack2(az, aw);
    *(uint2*)(outb + (size_t)v * D + lane * 4) = o;
}

// ---------------------------------------------------------------------------
// MFMA logits + fused argmax + H: A = relu(af2) bf16, B = lin1_w (fp32 256x64,
// frags built in-register). Wave w handles rows [stripe + w*16, +16).
// ---------------------------------------------------------------------------
__global__ __launch_bounds__(256, 2)
void logits_mfma(const unsigned short* __restrict__ af2, const float* __restrict__ Wl,
                 const float* __restrict__ bl, float* __restrict__ H,
                 int M, int Nn, int nStripes)
{
    __shared__ unsigned short Asm[64 * 264];
    int t = threadIdx.x, w = t >> 6, lane = t & 63;
    int n15 = lane & 15, quad = lane >> 4;

    s16x8 bfr[4][8];
#pragma unroll
    for (int nt = 0; nt < 4; nt++)
#pragma unroll
        for (int ks = 0; ks < 8; ks++) {
            s16x8 f;
#pragma unroll
            for (int j = 0; j < 8; j++) {
                int k = ks * 32 + quad * 8 + j;
                f[j] = (short)f2bf(Wl[(size_t)k * NS + nt * 16 + n15]);
            }
            bfr[nt][ks] = f;
        }
    float bcol[4];
#pragma unroll
    for (int nt = 0; nt < 4; nt++) bcol[nt] = bl[nt * 16 + n15];

    for (int s = blockIdx.x; s < nStripes; s += gridDim.x) {
        int m0 = s * 64;
        __syncthreads();
#pragma unroll
        for (int i = 0; i < 8; i++) {
            int idx = i * 256 + t;
            int m = idx >> 5, kc = (idx & 31) * 8;
            int gm = m0 + m;
            uint4 v = make_uint4(0u, 0u, 0u, 0u);
            if (gm < M) {
                v = *(const uint4*)(af2 + (size_t)gm * 256 + kc);
                v.x = relu2(v.x); v.y = relu2(v.y);
                v.z = relu2(v.z); v.w = relu2(v.w);
            }
            *(uint4*)(Asm + m * 264 + kc) = v;
        }
        __syncthreads();

        f32x4 acc[4];
#pragma unroll
        for (int nt = 0; nt < 4; nt++)
#pragma unroll
            for (int e = 0; e < 4; e++) acc[nt][e] = 0.f;

        int abase = (w * 16 + n15) * 264 + quad * 8;
#pragma unroll
        for (int ks = 0; ks < 8; ks++) {
            s16x8 a = *(const s16x8*)(Asm + abase + ks * 32);
#pragma unroll
            for (int nt = 0; nt < 4; nt++)
                acc[nt] = __builtin_amdgcn_mfma_f32_16x16x32_bf16(
                    a, bfr[nt][ks], acc[nt], 0, 0, 0);
        }

        // per-row argmax (first-index ties), rows = m0 + w*16 + quad*4 + e
#pragma unroll
        for (int e = 0; e < 4; e++) {
            float bv = acc[0][e] + bcol[0]; int bi = n15;
#pragma unroll
            for (int nt = 1; nt < 4; nt++) {
                float v = acc[nt][e] + bcol[nt];
                int c = nt * 16 + n15;
                if (v > bv) { bv = v; bi = c; }
            }
#pragma unroll
            for (int off = 1; off < 16; off <<= 1) {
                float ov = __shfl_xor(bv, off);
                int   oi = __shfl_xor(bi, off);
                if (ov > bv || (ov == bv && oi < bi)) { bv = ov; bi = oi; }
            }
            if (n15 == 0) {
                int gr = m0 + w * 16 + quad * 4 + e;
                if (gr < M) atomicAdd(H + (size_t)(gr % Nn) * NS + bi, 1.0f);
            }
        }
    }
}

// ---------------------------------------------------------------------------
// he[c] = sum_{n: H[n,c]>0} af2[n]
// ---------------------------------------------------------------------------
__global__ __launch_bounds__(64)
void he_kernel(const float* __restrict__ H, const unsigned short* __restrict__ af2,
               float* __restrict__ he, int Nn)
{
    __shared__ float acc[NS * D];   // 64 KiB
    int lane = threadIdx.x;
    for (int i = lane * 4; i < NS * D; i += 256)
        *(float4*)(acc + i) = make_float4(0.f, 0.f, 0.f, 0.f);
    __syncthreads();
    int n0 = blockIdx.x * 128;
    int n1 = min(n0 + 128, Nn);
    for (int n = n0; n < n1; n++) {
        float hv = H[(size_t)n * NS + lane];
        unsigned long long m = __ballot(hv > 0.f);
        if (!m) continue;
        uint2 q = *(const uint2*)(af2 + (size_t)n * D + lane * 4);
        float x0 = bflo(q.x), x1 = bfhi(q.x), x2 = bflo(q.y), x3 = bfhi(q.y);
        while (m) {
            int c = __ffsll(m) - 1;
            m &= m - 1;
            float* p = acc + (size_t)c * D + lane * 4;
            p[0] += x0; p[1] += x1; p[2] += x2; p[3] += x3;
        }
    }
    __syncthreads();
    for (int i = lane; i < NS * D; i += 64) atomicAdd(he + i, acc[i]);
}

// ---------------------------------------------------------------------------
__global__ void bigb_copy(const float* __restrict__ he, float* __restrict__ BigB)
{
    int idx = blockIdx.x * 256 + threadIdx.x;
    if (idx < D * NS) {
        int d = idx >> 6, c = idx & 63;
        BigB[idx] = he[(size_t)c * D + d];
    }
}

__global__ __launch_bounds__(256)
void bigb_mm(const float* __restrict__ lin_w, const float* __restrict__ lin_b,
             const float* __restrict__ he, float* __restrict__ BigB,
             float* __restrict__ beta)
{
    int gw = (int)((blockIdx.x * 256 + threadIdx.x) >> 6);
    int lane = threadIdx.x & 63;
    const int totalA = T * D * NS;
    if (gw >= totalA + T * NS) return;
    const float* xrow; const float* hrow; float* outp;
    if (gw < totalA) {
        int t = gw / (D * NS); int rem = gw - t * D * NS;
        int d = rem / NS; int c = rem - d * NS;
        xrow = lin_w + ((size_t)t * D + d) * D;
        hrow = he + (size_t)c * D;
        outp = BigB + ((size_t)(t + 1) * D + d) * NS + c;
    } else {
        int i = gw - totalA; int t = i / NS; int c = i - t * NS;
        xrow = lin_b + (size_t)t * D;
        hrow = he + (size_t)c * D;
        outp = beta + (size_t)(t + 1) * NS + c;
    }
    float4 x = *(const float4*)(xrow + lane * 4);
    float4 h = *(const float4*)(hrow + lane * 4);
    float s = x.x * h.x + x.y * h.y + x.z * h.z + x.w * h.w;
#pragma unroll
    for (int off = 32; off; off >>= 1) s += __shfl_xor(s, off);
    if (lane == 0) *outp = s;
}

// ---------------------------------------------------------------------------
// MFMA dots: feat(fp32, staged->bf16) @ BigB[rho] (fp32 256x64, frags in-reg)
// grid (nBlk, 5). out = (acc + beta)*1/16, fp32.
// ---------------------------------------------------------------------------
__global__ __launch_bounds__(256, 2)
void dots_mfma(const float* __restrict__ feat, const float* __restrict__ BigB,
               const float* __restrict__ beta, float* __restrict__ dots,
               int Nn, int nStripes)
{
    __shared__ unsigned short Asm[64 * 264];
    int t = threadIdx.x, w = t >> 6, lane = t & 63;
    int n15 = lane & 15, quad = lane >> 4;
    int rho = blockIdx.y;
    const float* Bp = BigB + (size_t)rho * D * NS;

    s16x8 bfr[4][8];
#pragma unroll
    for (int nt = 0; nt < 4; nt++)
#pragma unroll
        for (int ks = 0; ks < 8; ks++) {
            s16x8 f;
#pragma unroll
            for (int j = 0; j < 8; j++) {
                int k = ks * 32 + quad * 8 + j;
                f[j] = (short)f2bf(Bp[(size_t)k * NS + nt * 16 + n15]);
            }
            bfr[nt][ks] = f;
        }
    float bcol[4];
#pragma unroll
    for (int nt = 0; nt < 4; nt++) bcol[nt] = beta[rho * NS + nt * 16 + n15];

    for (int s = blockIdx.x; s < nStripes; s += gridDim.x) {
        int m0 = s * 64;
        __syncthreads();
#pragma unroll
        for (int i = 0; i < 8; i++) {
            int idx = i * 256 + t;
            int m = idx >> 5, kc = (idx & 31) * 8;
            int gm = m0 + m;
            uint4 o = make_uint4(0u, 0u, 0u, 0u);
            if (gm < Nn) {
                float4 a = *(const float4*)(feat + (size_t)gm * 256 + kc);
                float4 b = *(const float4*)(feat + (size_t)gm * 256 + kc + 4);
                o.x = pack2(a.x, a.y); o.y = pack2(a.z, a.w);
                o.z = pack2(b.x, b.y); o.w = pack2(b.z, b.w);
            }
            *(uint4*)(Asm + m * 264 + kc) = o;
        }
        __syncthreads();

        f32x4 acc[4];
#pragma unroll
        for (int nt = 0; nt < 4; nt++)
#pragma unroll
            for (int e = 0; e < 4; e++) acc[nt][e] = 0.f;

        int abase = (w * 16 + n15) * 264 + quad * 8;
#pragma unroll
        for (int ks = 0; ks < 8; ks++) {
            s16x8 a = *(const s16x8*)(Asm + abase + ks * 32);
#pragma unroll
            for (int nt = 0; nt < 4; nt++)
                acc[nt] = __builtin_amdgcn_mfma_f32_16x16x32_bf16(
                    a, bfr[nt][ks], acc[nt], 0, 0, 0);
        }

#pragma unroll
        for (int e = 0; e < 4; e++) {
            int gr = m0 + w * 16 + quad * 4 + e;
            if (gr >= Nn) continue;
#pragma unroll
            for (int nt = 0; nt < 4; nt++) {
                int c = nt * 16 + n15;
                dots[((size_t)rho * Nn + gr) * NS + c] = (acc[nt][e] + bcol[nt]) * 0.0625f;
            }
        }
    }
}

// ---------------------------------------------------------------------------
extern "C" void kernel_launch(void* const* d_in, const int* in_sizes, int n_in,
                              void* d_out, int out_size, void* d_ws, size_t ws_size,
                              hipStream_t stream)
{
    const int*   edge_index = (const int*)d_in[0];
    const float* features   = (const float*)d_in[1];
    const float* lin_w      = (const float*)d_in[2];
    const float* lin_b      = (const float*)d_in[3];
    const float* gcn0_w     = (const float*)d_in[4];
    const float* gcn0_b     = (const float*)d_in[5];
    const float* gcn1_w     = (const float*)d_in[6];
    const float* gcn1_b     = (const float*)d_in[7];
    const float* lin1_w     = (const float*)d_in[8];
    const float* lin1_b     = (const float*)d_in[9];

    int E  = in_sizes[0] / 2;
    int Nn = in_sizes[1] / D;
    int n_total = (T + 1) * Nn;
    int Mrep = T * Nn;
    int colcap = 2 * E + (2 * T + 1) * Nn;

    const int* src = edge_index;
    const int* dst = edge_index + E;

    float* out_H    = (float*)d_out;
    float* out_he   = out_H + (size_t)Nn * NS;
    float* out_dots = out_he + (size_t)NS * D;

    // ---- ws carve: two big bf16 regions + BigB (~256.3 MB)
    char* ws = (char*)d_ws;
    auto carve = [&](size_t bytes) {
        char* p = ws; ws += (bytes + 255) & ~(size_t)255; return p;
    };
    unsigned short* R1   = (unsigned short*)carve((size_t)n_total * D * 2);
    unsigned short* R2   = (unsigned short*)carve((size_t)n_total * D * 2);
    float*          BigB = (float*)carve((size_t)(T + 1) * D * NS * 4);
    float*          beta = (float*)carve((size_t)(T + 1) * NS * 4);
    unsigned short* transformed = R2;   // prefix, dead before agg1

    // ---- scratch in the out_dots region (~58 MB of 64 MB; all dead before dots_mfma)
    char* sc = (char*)out_dots;
    auto carve2 = [&](size_t bytes) {
        char* p = sc; sc += (bytes + 255) & ~(size_t)255; return p;
    };
    float* tinv    = (float*)carve2((size_t)Mrep * 4);
    int*   best    = (int*)carve2((size_t)E * 4);
    int*   cnt     = (int*)carve2((size_t)n_total * 4);
    int*   rowptr  = (int*)carve2((size_t)(n_total + 1) * 4);
    int*   fill    = (int*)carve2((size_t)n_total * 4);
    float* dinv    = (float*)carve2((size_t)n_total * 4);
    int*   aux     = (int*)carve2(1024 * 4);
    int*   auxex   = (int*)carve2(1024 * 4);
    int*   col     = (int*)carve2((size_t)colcap * 4);
    float* val     = (float*)carve2((size_t)colcap * 4);
    unsigned short* featb  = (unsigned short*)carve2((size_t)Nn * D * 2);
    unsigned short* Wfrags = (unsigned short*)carve2((size_t)6 * 65536 * 2);
    int*   ecnt    = (int*)carve2((size_t)Nn * 4);
    int*   eptr    = (int*)carve2((size_t)(Nn + 1) * 4);
    int*   efill   = (int*)carve2((size_t)Nn * 4);
    uint2* esorted = (uint2*)carve2((size_t)E * 8);

    // ---- zero accumulators
    zero_kernel<<<512, 256, 0, stream>>>((uint32*)cnt, n_total);
    zero_kernel<<<512, 256, 0, stream>>>((uint32*)fill, n_total);
    zero_kernel<<<512, 256, 0, stream>>>((uint32*)ecnt, Nn);
    zero_kernel<<<512, 256, 0, stream>>>((uint32*)efill, Nn);
    zero_kernel<<<512, 256, 0, stream>>>((uint32*)out_H, (long long)Nn * NS + NS * D);
    zero_kernel<<<1, 256, 0, stream>>>((uint32*)beta, (T + 1) * NS);

    // 0. conversions
    wfrag_kernel<<<dim3(256, 6), 256, 0, stream>>>(gcn0_w, gcn1_w, lin_w, Wfrags);
    f2bf_kernel<<<2048, 256, 0, stream>>>(features, featb, (long long)Nn * D / 8);

    // 1. transformed[z] = featb @ lin_w[z] + lin_b[z]  (batched MFMA)
    int strN = (Nn + 63) / 64;
    gemm_mfma<<<dim3(512, T), 256, 0, stream>>>(featb, Wfrags + 2 * 65536, lin_b,
                                                transformed, Nn, strN);
    // 2. row norms
    tinv_kernel<<<(Mrep + 3) / 4, 256, 0, stream>>>(transformed, tinv, Mrep);

    // 3. edge sort by dst + grouped sim
    ehist_kernel<<<2048, 256, 0, stream>>>(dst, ecnt, E);
    int enb = (Nn + 255) / 256;
    scan_sums<<<enb, 256, 0, stream>>>(ecnt, aux, Nn);
    scan_aux<<<1, 1024, 0, stream>>>(aux, auxex, enb);
    scan_write<<<enb, 256, 0, stream>>>(ecnt, auxex, eptr, Nn);
    escatter_kernel<<<2048, 256, 0, stream>>>(src, dst, eptr, efill, esorted, E);
    sim2_kernel<<<(Nn + 3) / 4, 256, 0, stream>>>(esorted, eptr, featb, transformed,
                                                  tinv, best, Nn);

    // 4. big-graph CSR
    hist_kernel<<<2048, 256, 0, stream>>>(src, dst, best, cnt, E, Nn);
    dinv_kernel<<<(n_total + 255) / 256, 256, 0, stream>>>(cnt, dinv, n_total);
    int nb = (n_total + 255) / 256;
    scan_sums<<<nb, 256, 0, stream>>>(cnt, aux, n_total);
    scan_aux<<<1, 1024, 0, stream>>>(aux, auxex, nb);
    scan_write<<<nb, 256, 0, stream>>>(cnt, auxex, rowptr, n_total);
    scatter_kernel<<<2048, 256, 0, stream>>>(src, dst, best, rowptr, fill, dinv,
                                             col, val, E, Nn);

    // 5. layer 0
    int strT = (n_total + 63) / 64;
    agg_kernel<<<(n_total + 3) / 4, 256, 0, stream>>>(rowptr, col, val, featb,
                                                      transformed, Nn, R1, n_total);
    gemm_mfma<<<dim3(512, 1), 256, 0, stream>>>(R1, Wfrags, gcn0_b, R1, n_total, strT);

    // 6. layer 1
    agg_kernel<<<(n_total + 3) / 4, 256, 0, stream>>>(rowptr, col, val, R1,
                                                      R1, 0, R2, n_total);
    gemm_mfma<<<dim3(512, 1), 256, 0, stream>>>(R2, Wfrags + 65536, gcn1_b, R2,
                                                n_total, strT);

    // 7. classes + H (MFMA + fused argmax)
    logits_mfma<<<512, 256, 0, stream>>>(R2, lin1_w, lin1_b, out_H, n_total, Nn, strT);

    // 8. hyperedge features
    he_kernel<<<(Nn + 127) / 128, 64, 0, stream>>>(out_H, R2, out_he, Nn);

    // 9. dots (MFMA over 5 rho)
    bigb_copy<<<(D * NS + 255) / 256, 256, 0, stream>>>(out_he, BigB);
    bigb_mm<<<(T * D * NS + T * NS + 3) / 4, 256, 0, stream>>>(lin_w, lin_b, out_he,
                                                               BigB, beta);
    dots_mfma<<<dim3(160, 5), 256, 0, stream>>>(features, BigB, beta, out_dots,
                                                Nn, strN);
}

// Round 6
// 1367.814 us; speedup vs baseline: 3.5942x; 1.0445x over previous
//
#include <hip/hip_runtime.h>

#define D 256
#define T 4
#define NS 64

typedef unsigned int uint32;
typedef short s16x8 __attribute__((ext_vector_type(8)));
typedef float f32x4 __attribute__((ext_vector_type(4)));

// ---- bf16 helpers (manual RNE) --------------------------------------------
__device__ __forceinline__ float bflo(uint32 u) { return __uint_as_float(u << 16); }
__device__ __forceinline__ float bfhi(uint32 u) { return __uint_as_float(u & 0xffff0000u); }
__device__ __forceinline__ unsigned short f2bf(float x) {
    uint32 u = __float_as_uint(x);
    u = u + 0x7FFFu + ((u >> 16) & 1u);
    return (unsigned short)(u >> 16);
}
__device__ __forceinline__ uint32 pack2(float a, float b) {
    return (uint32)f2bf(a) | ((uint32)f2bf(b) << 16);
}
// relu on 2 packed bf16
__device__ __forceinline__ uint32 relu2(uint32 u) {
    uint32 s = u & 0x80008000u;
    uint32 m = ((s >> 15) ^ 0x00010001u) * 0xFFFFu;
    return u & m;
}

// ---------------------------------------------------------------------------
__global__ void zero_kernel(uint32* __restrict__ p, long long n)
{
    long long i = (long long)blockIdx.x * blockDim.x + threadIdx.x;
    long long st = (long long)gridDim.x * blockDim.x;
    for (; i < n; i += st) p[i] = 0u;
}

__global__ void f2bf_kernel(const float* __restrict__ in, unsigned short* __restrict__ out,
                            long long n8)
{
    long long i = (long long)blockIdx.x * blockDim.x + threadIdx.x;
    long long st = (long long)gridDim.x * blockDim.x;
    for (; i < n8; i += st) {
        float4 a = *(const float4*)(in + i * 8);
        float4 b = *(const float4*)(in + i * 8 + 4);
        uint4 o;
        o.x = pack2(a.x, a.y); o.y = pack2(a.z, a.w);
        o.z = pack2(b.x, b.y); o.w = pack2(b.z, b.w);
        *(uint4*)(out + i * 8) = o;
    }
}

// ---------------------------------------------------------------------------
// 6 weight matrices (gcn0, gcn1, lin_w[0..3]) fp32 256x256 -> B-frag-linear bf16
// ---------------------------------------------------------------------------
__global__ void wfrag_kernel(const float* __restrict__ g0, const float* __restrict__ g1,
                             const float* __restrict__ lw, unsigned short* __restrict__ out)
{
    int o = blockIdx.x * 256 + threadIdx.x;   // 0..65535
    int mat = blockIdx.y;
    const float* W = (mat == 0) ? g0 : (mat == 1) ? g1 : (lw + (size_t)(mat - 2) * 65536);
    int j = o & 7, lane = (o >> 3) & 63, ks = (o >> 9) & 7, nt = o >> 12;
    int n15 = lane & 15, quad = lane >> 4;
    int k = ks * 32 + quad * 8 + j;
    int n = nt * 16 + n15;
    out[(size_t)mat * 65536 + o] = f2bf(W[(size_t)k * 256 + n]);
}

// ---------------------------------------------------------------------------
// MFMA GEMM: C(bf16, Mx256) = A(bf16, Mx256) @ W(bf16 frag-linear) + bias.
// grid (nBlk, Z): z offsets Wfrag/bias/C (batched transformed). In-place safe.
// ---------------------------------------------------------------------------
__global__ __launch_bounds__(256, 2)
void gemm_mfma(const unsigned short* __restrict__ A,
               const unsigned short* __restrict__ Wfrag,
               const float* __restrict__ bias,
               unsigned short* __restrict__ Cout,
               int M, int nStripes)
{
    __shared__ unsigned short Asm[64 * 264];
    int t = threadIdx.x, w = t >> 6, lane = t & 63;
    int n15 = lane & 15, quad = lane >> 4;
    int z = blockIdx.y;
    Wfrag += (size_t)z * 65536;
    bias  += (size_t)z * 256;
    Cout  += (size_t)z * (size_t)M * 256;

    s16x8 bfr[4][8];
#pragma unroll
    for (int nt = 0; nt < 4; nt++)
#pragma unroll
        for (int ks = 0; ks < 8; ks++)
            bfr[nt][ks] = *(const s16x8*)(Wfrag +
                (size_t)(((w * 4 + nt) * 8 + ks) * 64 + lane) * 8);

    float bcol[4];
#pragma unroll
    for (int nt = 0; nt < 4; nt++) bcol[nt] = bias[(w * 4 + nt) * 16 + n15];

    for (int s = blockIdx.x; s < nStripes; s += gridDim.x) {
        int m0 = s * 64;
        __syncthreads();
#pragma unroll
        for (int i = 0; i < 8; i++) {
            int idx = i * 256 + t;
            int m = idx >> 5, kc = (idx & 31) * 8;
            int gm = m0 + m;
            uint4 v = make_uint4(0u, 0u, 0u, 0u);
            if (gm < M) v = *(const uint4*)(A + (size_t)gm * 256 + kc);
            *(uint4*)(Asm + m * 264 + kc) = v;
        }
        __syncthreads();

        f32x4 acc[4][4];
#pragma unroll
        for (int rt = 0; rt < 4; rt++)
#pragma unroll
            for (int nt = 0; nt < 4; nt++)
#pragma unroll
                for (int e = 0; e < 4; e++) acc[rt][nt][e] = 0.f;

#pragma unroll
        for (int rt = 0; rt < 4; rt++) {
            int abase = (rt * 16 + n15) * 264 + quad * 8;
#pragma unroll
            for (int ks = 0; ks < 8; ks++) {
                s16x8 a = *(const s16x8*)(Asm + abase + ks * 32);
#pragma unroll
                for (int nt = 0; nt < 4; nt++)
                    acc[rt][nt] = __builtin_amdgcn_mfma_f32_16x16x32_bf16(
                        a, bfr[nt][ks], acc[rt][nt], 0, 0, 0);
            }
        }

#pragma unroll
        for (int rt = 0; rt < 4; rt++) {
            int row0 = m0 + rt * 16 + quad * 4;
#pragma unroll
            for (int nt = 0; nt < 4; nt++) {
                int colp = (w * 4 + nt) * 16 + n15;
#pragma unroll
                for (int r = 0; r < 4; r++) {
                    int gr = row0 + r;
                    if (gr < M)
                        Cout[(size_t)gr * 256 + colp] = f2bf(acc[rt][nt][r] + bcol[nt]);
                }
            }
        }
    }
}

// ---------------------------------------------------------------------------
__global__ __launch_bounds__(256)
void tinv_kernel(const unsigned short* __restrict__ tr, float* __restrict__ tinv, int rows)
{
    int wave = threadIdx.x >> 6, lane = threadIdx.x & 63;
    int r = blockIdx.x * 4 + wave;
    if (r >= rows) return;
    uint2 q = *(const uint2*)(tr + (size_t)r * D + lane * 4);
    float a = bflo(q.x), b = bfhi(q.x), c = bflo(q.y), d = bfhi(q.y);
    float s = a * a + b * b + c * c + d * d;
#pragma unroll
    for (int off = 32; off; off >>= 1) s += __shfl_xor(s, off);
    if (lane == 0) tinv[r] = 1.f / fmaxf(sqrtf(s), 1e-8f);
}

// ---------------------------------------------------------------------------
// edge counting sort by dst; esorted = (src, dst) pairs in dst order
// ---------------------------------------------------------------------------
__global__ void ehist_kernel(const int* __restrict__ dst, int* __restrict__ ecnt, int E)
{
    for (int e = blockIdx.x * blockDim.x + threadIdx.x; e < E;
         e += gridDim.x * blockDim.x)
        atomicAdd(ecnt + dst[e], 1);
}

__global__ void escatter_kernel(const int* __restrict__ src, const int* __restrict__ dst,
                                const int* __restrict__ eptr, int* __restrict__ efill,
                                uint2* __restrict__ esorted, int E)
{
    for (int e = blockIdx.x * blockDim.x + threadIdx.x; e < E;
         e += gridDim.x * blockDim.x) {
        int d = dst[e];
        int pos = eptr[d] + atomicAdd(efill + d, 1);
        esorted[pos] = make_uint2((uint32)src[e], (uint32)d);
    }
}

// ---------------------------------------------------------------------------
// sim via MFMA diagonal: 16 sorted edges per wave.
// A[m][k] = featb[src_m][k]  (m = lane&15, k-slice quad*8)
// B[n][k] = tr[i][dst_n][k]  -> C[m][n] = feat_m . tr_n ; diagonal = per-edge dot.
// Diagonal lanes (quad == n15>>2) do the argmax locally; best in SORTED order.
// ---------------------------------------------------------------------------
__global__ __launch_bounds__(256)
void sim3_kernel(const uint2* __restrict__ esorted,
                 const unsigned short* __restrict__ featb,
                 const unsigned short* __restrict__ tr, const float* __restrict__ tinv,
                 int* __restrict__ bestS, int E, int Nn)
{
    int w = threadIdx.x >> 6, lane = threadIdx.x & 63;
    int n15 = lane & 15, quad = lane >> 4;
    int base = (blockIdx.x * 4 + w) * 16;
    if (base >= E) return;
    int ei = min(base + n15, E - 1);
    uint2 se = esorted[ei];
    const unsigned short* arow = featb + (size_t)se.x * D + quad * 8;
    const unsigned short* brow = tr + (size_t)se.y * D + quad * 8;   // replica 0
    size_t rstride = (size_t)Nn * D;

    f32x4 a0 = {0.f, 0.f, 0.f, 0.f}, a1 = a0, a2 = a0, a3 = a0;
#pragma unroll
    for (int ks = 0; ks < 8; ks++) {
        s16x8 a  = *(const s16x8*)(arow + ks * 32);
        s16x8 b0 = *(const s16x8*)(brow + ks * 32);
        s16x8 b1 = *(const s16x8*)(brow + rstride + ks * 32);
        s16x8 b2 = *(const s16x8*)(brow + 2 * rstride + ks * 32);
        s16x8 b3 = *(const s16x8*)(brow + 3 * rstride + ks * 32);
        a0 = __builtin_amdgcn_mfma_f32_16x16x32_bf16(a, b0, a0, 0, 0, 0);
        a1 = __builtin_amdgcn_mfma_f32_16x16x32_bf16(a, b1, a1, 0, 0, 0);
        a2 = __builtin_amdgcn_mfma_f32_16x16x32_bf16(a, b2, a2, 0, 0, 0);
        a3 = __builtin_amdgcn_mfma_f32_16x16x32_bf16(a, b3, a3, 0, 0, 0);
    }
    if (quad == (n15 >> 2) && base + n15 < E) {
        int r = n15 & 3;
        int d = (int)se.y;
        float v0 = a0[r] * tinv[d];
        float v1 = a1[r] * tinv[Nn + d];
        float v2 = a2[r] * tinv[2 * Nn + d];
        float v3 = a3[r] * tinv[3 * Nn + d];
        float bv = v0; int bi = 0;
        if (v1 > bv) { bv = v1; bi = 1; }   // strict >: first-index ties
        if (v2 > bv) { bv = v2; bi = 2; }
        if (v3 > bv) { bv = v3; bi = 3; }
        bestS[base + n15] = bi;
    }
}

// ---------------------------------------------------------------------------
// unified edge list over SORTED edges: [0,E) copy1, [E,2E) rewired copy,
// [2E,2E+T*N) identity, then n_total self loops. keep == (weight != 0).
// ---------------------------------------------------------------------------
__device__ __forceinline__ void decode_edge(int e, const uint2* __restrict__ esorted,
                                            const int* __restrict__ bestS,
                                            int E, int Nn, int& s, int& d, bool& keep)
{
    if (e < E) {
        uint2 se = esorted[e];
        s = (int)se.x; d = (int)se.y; keep = (s != d);
    } else if (e < 2 * E) {
        int k = e - E;
        uint2 se = esorted[k];
        s = (int)se.x; d = (int)se.y + bestS[k] * Nn; keep = (s != d);
    } else if (e < 2 * E + T * Nn) {
        int k = e - 2 * E; int i = k / Nn; int n = k - i * Nn;
        s = n; d = n + i * Nn; keep = (i != 0);
    } else {
        int v = e - (2 * E + T * Nn); s = v; d = v; keep = true;
    }
}

__global__ void hist_kernel(const uint2* __restrict__ esorted, const int* __restrict__ bestS,
                            int* __restrict__ cnt, int E, int Nn)
{
    int total = 2 * E + (2 * T + 1) * Nn;
    for (int e = blockIdx.x * blockDim.x + threadIdx.x; e < total;
         e += gridDim.x * blockDim.x) {
        int s, d; bool keep;
        decode_edge(e, esorted, bestS, E, Nn, s, d, keep);
        if (keep) atomicAdd(cnt + d, 1);
    }
}

__global__ void dinv_kernel(const int* __restrict__ cnt, float* __restrict__ dinv, int n)
{
    int v = blockIdx.x * blockDim.x + threadIdx.x;
    if (v < n) dinv[v] = (cnt[v] > 0) ? rsqrtf((float)cnt[v]) : 0.f;
}

__global__ void scan_sums(const int* __restrict__ cnt, int* __restrict__ aux, int n)
{
    __shared__ int sd[256];
    int idx = blockIdx.x * 256 + threadIdx.x;
    sd[threadIdx.x] = (idx < n) ? cnt[idx] : 0;
    __syncthreads();
    for (int off = 128; off; off >>= 1) {
        if (threadIdx.x < off) sd[threadIdx.x] += sd[threadIdx.x + off];
        __syncthreads();
    }
    if (threadIdx.x == 0) aux[blockIdx.x] = sd[0];
}

__global__ void scan_aux(const int* __restrict__ aux, int* __restrict__ auxex, int nb)
{
    __shared__ int sd[1024];
    int t = threadIdx.x;
    int v = (t < nb) ? aux[t] : 0;
    sd[t] = v;
    __syncthreads();
    for (int off = 1; off < 1024; off <<= 1) {
        int x = (t >= off) ? sd[t - off] : 0;
        __syncthreads();
        sd[t] += x;
        __syncthreads();
    }
    if (t < nb) auxex[t] = sd[t] - v;
}

__global__ void scan_write(const int* __restrict__ cnt, const int* __restrict__ auxex,
                           int* __restrict__ rowptr, int n)
{
    __shared__ int sd[256];
    int t = threadIdx.x;
    int idx = blockIdx.x * 256 + t;
    int v = (idx < n) ? cnt[idx] : 0;
    sd[t] = v;
    __syncthreads();
    for (int off = 1; off < 256; off <<= 1) {
        int x = (t >= off) ? sd[t - off] : 0;
        __syncthreads();
        sd[t] += x;
        __syncthreads();
    }
    if (idx < n) {
        int rp = auxex[blockIdx.x] + sd[t] - v;
        rowptr[idx] = rp;
        if (idx == n - 1) rowptr[n] = rp + v;
    }
}

__global__ void scatter_kernel(const uint2* __restrict__ esorted, const int* __restrict__ bestS,
                               const int* __restrict__ rowptr, int* __restrict__ fill,
                               const float* __restrict__ dinv,
                               int* __restrict__ col, float* __restrict__ val,
                               int E, int Nn)
{
    int total = 2 * E + (2 * T + 1) * Nn;
    for (int e = blockIdx.x * blockDim.x + threadIdx.x; e < total;
         e += gridDim.x * blockDim.x) {
        int s, d; bool keep;
        decode_edge(e, esorted, bestS, E, Nn, s, d, keep);
        if (keep) {
            int pos = rowptr[d] + atomicAdd(fill + d, 1);
            col[pos] = s;
            val[pos] = dinv[s] * dinv[d];
        }
    }
}

// ---------------------------------------------------------------------------
// aggregate-first: out[v] = sum_j val[j]*relu(x[col[j]]), x bf16 split across
// xa [0,split) / xb [split,...). unroll x2 (two gathers in flight).
// ---------------------------------------------------------------------------
__global__ __launch_bounds__(256)
void agg_kernel(const int* __restrict__ rowptr, const int* __restrict__ col,
                const float* __restrict__ val,
                const unsigned short* __restrict__ xa,
                const unsigned short* __restrict__ xb, int split,
                unsigned short* __restrict__ outb, int n_total)
{
    int wave = threadIdx.x >> 6, lane = threadIdx.x & 63;
    int v = blockIdx.x * 4 + wave;
    if (v >= n_total) return;
    int j0 = rowptr[v], j1 = rowptr[v + 1];
    float ax = 0.f, ay = 0.f, az = 0.f, aw = 0.f;
    int j = j0;
    for (; j + 2 <= j1; j += 2) {
        int s0 = col[j], s1 = col[j + 1];
        float w0 = val[j], w1 = val[j + 1];
        const unsigned short* p0 = (s0 < split) ? (xa + (size_t)s0 * D)
                                                : (xb + (size_t)(s0 - split) * D);
        const unsigned short* p1 = (s1 < split) ? (xa + (size_t)s1 * D)
                                                : (xb + (size_t)(s1 - split) * D);
        uint2 q0 = *(const uint2*)(p0 + lane * 4);
        uint2 q1 = *(const uint2*)(p1 + lane * 4);
        q0.x = relu2(q0.x); q0.y = relu2(q0.y);
        q1.x = relu2(q1.x); q1.y = relu2(q1.y);
        ax = fmaf(w0, bflo(q0.x), ax); ay = fmaf(w0, bfhi(q0.x), ay);
        az = fmaf(w0, bflo(q0.y), az); aw = fmaf(w0, bfhi(q0.y), aw);
        ax = fmaf(w1, bflo(q1.x), ax); ay = fmaf(w1, bfhi(q1.x), ay);
        az = fmaf(w1, bflo(q1.y), az); aw = fmaf(w1, bfhi(q1.y), aw);
    }
    if (j < j1) {
        int s0 = col[j];
        float w0 = val[j];
        const unsigned short* p0 = (s0 < split) ? (xa + (size_t)s0 * D)
                                                : (xb + (size_t)(s0 - split) * D);
        uint2 q0 = *(const uint2*)(p0 + lane * 4);
        q0.x = relu2(q0.x); q0.y = relu2(q0.y);
        ax = fmaf(w0, bflo(q0.x), ax); ay = fmaf(w0, bfhi(q0.x), ay);
        az = fmaf(w0, bflo(q0.y), az); aw = fmaf(w0, bfhi(q0.y), aw);
    }
    uint2 o; o.x = pack2(ax, ay); o.y = pack2(az, aw);
    *(uint2*)(outb + (size_t)v * D + lane * 4) = o;
}

// ---------------------------------------------------------------------------
// MFMA logits + fused argmax + H
// ---------------------------------------------------------------------------
__global__ __launch_bounds__(256, 2)
void logits_mfma(const unsigned short* __restrict__ af2, const float* __restrict__ Wl,
                 const float* __restrict__ bl, float* __restrict__ H,
                 int M, int Nn, int nStripes)
{
    __shared__ unsigned short Asm[64 * 264];
    int t = threadIdx.x, w = t >> 6, lane = t & 63;
    int n15 = lane & 15, quad = lane >> 4;

    s16x8 bfr[4][8];
#pragma unroll
    for (int nt = 0; nt < 4; nt++)
#pragma unroll
        for (int ks = 0; ks < 8; ks++) {
            s16x8 f;
#pragma unroll
            for (int j = 0; j < 8; j++) {
                int k = ks * 32 + quad * 8 + j;
                f[j] = (short)f2bf(Wl[(size_t)k * NS + nt * 16 + n15]);
            }
            bfr[nt][ks] = f;
        }
    float bcol[4];
#pragma unroll
    for (int nt = 0; nt < 4; nt++) bcol[nt] = bl[nt * 16 + n15];

    for (int s = blockIdx.x; s < nStripes; s += gridDim.x) {
        int m0 = s * 64;
        __syncthreads();
#pragma unroll
        for (int i = 0; i < 8; i++) {
            int idx = i * 256 + t;
            int m = idx >> 5, kc = (idx & 31) * 8;
            int gm = m0 + m;
            uint4 v = make_uint4(0u, 0u, 0u, 0u);
            if (gm < M) {
                v = *(const uint4*)(af2 + (size_t)gm * 256 + kc);
                v.x = relu2(v.x); v.y = relu2(v.y);
                v.z = relu2(v.z); v.w = relu2(v.w);
            }
            *(uint4*)(Asm + m * 264 + kc) = v;
        }
        __syncthreads();

        f32x4 acc[4];
#pragma unroll
        for (int nt = 0; nt < 4; nt++)
#pragma unroll
            for (int e = 0; e < 4; e++) acc[nt][e] = 0.f;

        int abase = (w * 16 + n15) * 264 + quad * 8;
#pragma unroll
        for (int ks = 0; ks < 8; ks++) {
            s16x8 a = *(const s16x8*)(Asm + abase + ks * 32);
#pragma unroll
            for (int nt = 0; nt < 4; nt++)
                acc[nt] = __builtin_amdgcn_mfma_f32_16x16x32_bf16(
                    a, bfr[nt][ks], acc[nt], 0, 0, 0);
        }

#pragma unroll
        for (int e = 0; e < 4; e++) {
            float bv = acc[0][e] + bcol[0]; int bi = n15;
#pragma unroll
            for (int nt = 1; nt < 4; nt++) {
                float v = acc[nt][e] + bcol[nt];
                int c = nt * 16 + n15;
                if (v > bv) { bv = v; bi = c; }
            }
#pragma unroll
            for (int off = 1; off < 16; off <<= 1) {
                float ov = __shfl_xor(bv, off);
                int   oi = __shfl_xor(bi, off);
                if (ov > bv || (ov == bv && oi < bi)) { bv = ov; bi = oi; }
            }
            if (n15 == 0) {
                int gr = m0 + w * 16 + quad * 4 + e;
                if (gr < M) atomicAdd(H + (size_t)(gr % Nn) * NS + bi, 1.0f);
            }
        }
    }
}

// ---------------------------------------------------------------------------
// he[c] = sum_{n: H[n,c]>0} af2[n]
// ---------------------------------------------------------------------------
__global__ __launch_bounds__(64)
void he_kernel(const float* __restrict__ H, const unsigned short* __restrict__ af2,
               float* __restrict__ he, int Nn)
{
    __shared__ float acc[NS * D];   // 64 KiB
    int lane = threadIdx.x;
    for (int i = lane * 4; i < NS * D; i += 256)
        *(float4*)(acc + i) = make_float4(0.f, 0.f, 0.f, 0.f);
    __syncthreads();
    int n0 = blockIdx.x * 128;
    int n1 = min(n0 + 128, Nn);
    for (int n = n0; n < n1; n++) {
        float hv = H[(size_t)n * NS + lane];
        unsigned long long m = __ballot(hv > 0.f);
        if (!m) continue;
        uint2 q = *(const uint2*)(af2 + (size_t)n * D + lane * 4);
        float x0 = bflo(q.x), x1 = bfhi(q.x), x2 = bflo(q.y), x3 = bfhi(q.y);
        while (m) {
            int c = __ffsll(m) - 1;
            m &= m - 1;
            float* p = acc + (size_t)c * D + lane * 4;
            p[0] += x0; p[1] += x1; p[2] += x2; p[3] += x3;
        }
    }
    __syncthreads();
    for (int i = lane; i < NS * D; i += 64) atomicAdd(he + i, acc[i]);
}

// ---------------------------------------------------------------------------
__global__ void bigb_copy(const float* __restrict__ he, float* __restrict__ BigB)
{
    int idx = blockIdx.x * 256 + threadIdx.x;
    if (idx < D * NS) {
        int d = idx >> 6, c = idx & 63;
        BigB[idx] = he[(size_t)c * D + d];
    }
}

__global__ __launch_bounds__(256)
void bigb_mm(const float* __restrict__ lin_w, const float* __restrict__ lin_b,
             const float* __restrict__ he, float* __restrict__ BigB,
             float* __restrict__ beta)
{
    int gw = (int)((blockIdx.x * 256 + threadIdx.x) >> 6);
    int lane = threadIdx.x & 63;
    const int totalA = T * D * NS;
    if (gw >= totalA + T * NS) return;
    const float* xrow; const float* hrow; float* outp;
    if (gw < totalA) {
        int t = gw / (D * NS); int rem = gw - t * D * NS;
        int d = rem / NS; int c = rem - d * NS;
        xrow = lin_w + ((size_t)t * D + d) * D;
        hrow = he + (size_t)c * D;
        outp = BigB + ((size_t)(t + 1) * D + d) * NS + c;
    } else {
        int i = gw - totalA; int t = i / NS; int c = i - t * NS;
        xrow = lin_b + (size_t)t * D;
        hrow = he + (size_t)c * D;
        outp = beta + (size_t)(t + 1) * NS + c;
    }
    float4 x = *(const float4*)(xrow + lane * 4);
    float4 h = *(const float4*)(hrow + lane * 4);
    float s = x.x * h.x + x.y * h.y + x.z * h.z + x.w * h.w;
#pragma unroll
    for (int off = 32; off; off >>= 1) s += __shfl_xor(s, off);
    if (lane == 0) *outp = s;
}

// ---------------------------------------------------------------------------
// MFMA dots: feat(fp32, staged->bf16) @ BigB[rho], grid (nBlk, 5)
// ---------------------------------------------------------------------------
__global__ __launch_bounds__(256, 2)
void dots_mfma(const float* __restrict__ feat, const float* __restrict__ BigB,
               const float* __restrict__ beta, float* __restrict__ dots,
               int Nn, int nStripes)
{
    __shared__ unsigned short Asm[64 * 264];
    int t = threadIdx.x, w = t >> 6, lane = t & 63;
    int n15 = lane & 15, quad = lane >> 4;
    int rho = blockIdx.y;
    const float* Bp = BigB + (size_t)rho * D * NS;

    s16x8 bfr[4][8];
#pragma unroll
    for (int nt = 0; nt < 4; nt++)
#pragma unroll
        for (int ks = 0; ks < 8; ks++) {
            s16x8 f;
#pragma unroll
            for (int j = 0; j < 8; j++) {
                int k = ks * 32 + quad * 8 + j;
                f[j] = (short)f2bf(Bp[(size_t)k * NS + nt * 16 + n15]);
            }
            bfr[nt][ks] = f;
        }
    float bcol[4];
#pragma unroll
    for (int nt = 0; nt < 4; nt++) bcol[nt] = beta[rho * NS + nt * 16 + n15];

    for (int s = blockIdx.x; s < nStripes; s += gridDim.x) {
        int m0 = s * 64;
        __syncthreads();
#pragma unroll
        for (int i = 0; i < 8; i++) {
            int idx = i * 256 + t;
            int m = idx >> 5, kc = (idx & 31) * 8;
            int gm = m0 + m;
            uint4 o = make_uint4(0u, 0u, 0u, 0u);
            if (gm < Nn) {
                float4 a = *(const float4*)(feat + (size_t)gm * 256 + kc);
                float4 b = *(const float4*)(feat + (size_t)gm * 256 + kc + 4);
                o.x = pack2(a.x, a.y); o.y = pack2(a.z, a.w);
                o.z = pack2(b.x, b.y); o.w = pack2(b.z, b.w);
            }
            *(uint4*)(Asm + m * 264 + kc) = o;
        }
        __syncthreads();

        f32x4 acc[4];
#pragma unroll
        for (int nt = 0; nt < 4; nt++)
#pragma unroll
            for (int e = 0; e < 4; e++) acc[nt][e] = 0.f;

        int abase = (w * 16 + n15) * 264 + quad * 8;
#pragma unroll
        for (int ks = 0; ks < 8; ks++) {
            s16x8 a = *(const s16x8*)(Asm + abase + ks * 32);
#pragma unroll
            for (int nt = 0; nt < 4; nt++)
                acc[nt] = __builtin_amdgcn_mfma_f32_16x16x32_bf16(
                    a, bfr[nt][ks], acc[nt], 0, 0, 0);
        }

#pragma unroll
        for (int e = 0; e < 4; e++) {
            int gr = m0 + w * 16 + quad * 4 + e;
            if (gr >= Nn) continue;
#pragma unroll
            for (int nt = 0; nt < 4; nt++) {
                int c = nt * 16 + n15;
                dots[((size_t)rho * Nn + gr) * NS + c] = (acc[nt][e] + bcol[nt]) * 0.0625f;
            }
        }
    }
}

// ---------------------------------------------------------------------------
extern "C" void kernel_launch(void* const* d_in, const int* in_sizes, int n_in,
                              void* d_out, int out_size, void* d_ws, size_t ws_size,
                              hipStream_t stream)
{
    const int*   edge_index = (const int*)d_in[0];
    const float* features   = (const float*)d_in[1];
    const float* lin_w      = (const float*)d_in[2];
    const float* lin_b      = (const float*)d_in[3];
    const float* gcn0_w     = (const float*)d_in[4];
    const float* gcn0_b     = (const float*)d_in[5];
    const float* gcn1_w     = (const float*)d_in[6];
    const float* gcn1_b     = (const float*)d_in[7];
    const float* lin1_w     = (const float*)d_in[8];
    const float* lin1_b     = (const float*)d_in[9];

    int E  = in_sizes[0] / 2;
    int Nn = in_sizes[1] / D;
    int n_total = (T + 1) * Nn;
    int Mrep = T * Nn;
    int colcap = 2 * E + (2 * T + 1) * Nn;

    const int* src = edge_index;
    const int* dst = edge_index + E;

    float* out_H    = (float*)d_out;
    float* out_he   = out_H + (size_t)Nn * NS;
    float* out_dots = out_he + (size_t)NS * D;

    // ---- ws carve: two big bf16 regions + BigB (~256.3 MB)
    char* ws = (char*)d_ws;
    auto carve = [&](size_t bytes) {
        char* p = ws; ws += (bytes + 255) & ~(size_t)255; return p;
    };
    unsigned short* R1   = (unsigned short*)carve((size_t)n_total * D * 2);
    unsigned short* R2   = (unsigned short*)carve((size_t)n_total * D * 2);
    float*          BigB = (float*)carve((size_t)(T + 1) * D * NS * 4);
    float*          beta = (float*)carve((size_t)(T + 1) * NS * 4);
    unsigned short* transformed = R2;   // prefix, dead before agg1

    // ---- scratch in the out_dots region (~58 MB of 64 MB; dead before dots_mfma)
    char* sc = (char*)out_dots;
    auto carve2 = [&](size_t bytes) {
        char* p = sc; sc += (bytes + 255) & ~(size_t)255; return p;
    };
    float* tinv    = (float*)carve2((size_t)Mrep * 4);
    int*   best    = (int*)carve2((size_t)E * 4);       // SORTED order
    int*   cnt     = (int*)carve2((size_t)n_total * 4);
    int*   rowptr  = (int*)carve2((size_t)(n_total + 1) * 4);
    int*   fill    = (int*)carve2((size_t)n_total * 4);
    float* dinv    = (float*)carve2((size_t)n_total * 4);
    int*   aux     = (int*)carve2(1024 * 4);
    int*   auxex   = (int*)carve2(1024 * 4);
    int*   col     = (int*)carve2((size_t)colcap * 4);
    float* val     = (float*)carve2((size_t)colcap * 4);
    unsigned short* featb  = (unsigned short*)carve2((size_t)Nn * D * 2);
    unsigned short* Wfrags = (unsigned short*)carve2((size_t)6 * 65536 * 2);
    int*   ecnt    = (int*)carve2((size_t)Nn * 4);
    int*   eptr    = (int*)carve2((size_t)(Nn + 1) * 4);
    int*   efill   = (int*)carve2((size_t)Nn * 4);
    uint2* esorted = (uint2*)carve2((size_t)E * 8);     // (src, dst) in dst order

    // ---- zero accumulators
    zero_kernel<<<512, 256, 0, stream>>>((uint32*)cnt, n_total);
    zero_kernel<<<512, 256, 0, stream>>>((uint32*)fill, n_total);
    zero_kernel<<<512, 256, 0, stream>>>((uint32*)ecnt, Nn);
    zero_kernel<<<512, 256, 0, stream>>>((uint32*)efill, Nn);
    zero_kernel<<<512, 256, 0, stream>>>((uint32*)out_H, (long long)Nn * NS + NS * D);
    zero_kernel<<<1, 256, 0, stream>>>((uint32*)beta, (T + 1) * NS);

    // 0. conversions
    wfrag_kernel<<<dim3(256, 6), 256, 0, stream>>>(gcn0_w, gcn1_w, lin_w, Wfrags);
    f2bf_kernel<<<2048, 256, 0, stream>>>(features, featb, (long long)Nn * D / 8);

    // 1. transformed[z] = featb @ lin_w[z] + lin_b[z]  (batched MFMA)
    int strN = (Nn + 63) / 64;
    gemm_mfma<<<dim3(512, T), 256, 0, stream>>>(featb, Wfrags + 2 * 65536, lin_b,
                                                transformed, Nn, strN);
    // 2. row norms
    tinv_kernel<<<(Mrep + 3) / 4, 256, 0, stream>>>(transformed, tinv, Mrep);

    // 3. edge sort by dst + MFMA-diagonal sim
    ehist_kernel<<<2048, 256, 0, stream>>>(dst, ecnt, E);
    int enb = (Nn + 255) / 256;
    scan_sums<<<enb, 256, 0, stream>>>(ecnt, aux, Nn);
    scan_aux<<<1, 1024, 0, stream>>>(aux, auxex, enb);
    scan_write<<<enb, 256, 0, stream>>>(ecnt, auxex, eptr, Nn);
    escatter_kernel<<<2048, 256, 0, stream>>>(src, dst, eptr, efill, esorted, E);
    int nGroups = (E + 15) / 16;
    sim3_kernel<<<(nGroups + 3) / 4, 256, 0, stream>>>(esorted, featb, transformed,
                                                       tinv, best, E, Nn);

    // 4. big-graph CSR (over sorted edges — order-invariant bag)
    hist_kernel<<<2048, 256, 0, stream>>>(esorted, best, cnt, E, Nn);
    dinv_kernel<<<(n_total + 255) / 256, 256, 0, stream>>>(cnt, dinv, n_total);
    int nb = (n_total + 255) / 256;
    scan_sums<<<nb, 256, 0, stream>>>(cnt, aux, n_total);
    scan_aux<<<1, 1024, 0, stream>>>(aux, auxex, nb);
    scan_write<<<nb, 256, 0, stream>>>(cnt, auxex, rowptr, n_total);
    scatter_kernel<<<2048, 256, 0, stream>>>(esorted, best, rowptr, fill, dinv,
                                             col, val, E, Nn);

    // 5. layer 0
    int strT = (n_total + 63) / 64;
    agg_kernel<<<(n_total + 3) / 4, 256, 0, stream>>>(rowptr, col, val, featb,
                                                      transformed, Nn, R1, n_total);
    gemm_mfma<<<dim3(512, 1), 256, 0, stream>>>(R1, Wfrags, gcn0_b, R1, n_total, strT);

    // 6. layer 1
    agg_kernel<<<(n_total + 3) / 4, 256, 0, stream>>>(rowptr, col, val, R1,
                                                      R1, 0, R2, n_total);
    gemm_mfma<<<dim3(512, 1), 256, 0, stream>>>(R2, Wfrags + 65536, gcn1_b, R2,
                                                n_total, strT);

    // 7. classes + H (MFMA + fused argmax)
    logits_mfma<<<512, 256, 0, stream>>>(R2, lin1_w, lin1_b, out_H, n_total, Nn, strT);

    // 8. hyperedge features
    he_kernel<<<(Nn + 127) / 128, 64, 0, stream>>>(out_H, R2, out_he, Nn);

    // 9. dots (MFMA over 5 rho)
    bigb_copy<<<(D * NS + 255) / 256, 256, 0, stream>>>(out_he, BigB);
    bigb_mm<<<(T * D * NS + T * NS + 3) / 4, 256, 0, stream>>>(lin_w, lin_b, out_he,
                                                               BigB, beta);
    dots_mfma<<<dim3(160, 5), 256, 0, stream>>>(features, BigB, beta, out_dots,
                                                Nn, strN);
}